// Round 6
// baseline (1375.697 us; speedup 1.0000x reference)
//
#include <hip/hip_runtime.h>

#define N_NODES 100000
#define N_EDGES 1600000
#define HID 256

typedef _Float16 half_t;
using f16x8 = __attribute__((ext_vector_type(8))) half_t;
using f16x4 = __attribute__((ext_vector_type(4))) half_t;
using f32x4 = __attribute__((ext_vector_type(4))) float;

constexpr int SCAN_CHUNK = 1024;
constexpr int NBLK = (N_NODES + SCAN_CHUNK - 1) / SCAN_CHUNK; // 98

// ---------------- CSR build ----------------
__global__ void k_count(const int* __restrict__ dst, int* __restrict__ deg) {
    int e = blockIdx.x * 256 + threadIdx.x;
    if (e < N_EDGES) atomicAdd(&deg[dst[e]], 1);
}

__global__ void k_blocksum(const int* __restrict__ deg, int* __restrict__ bsum) {
    __shared__ int sm[4];
    int b = blockIdx.x, t = threadIdx.x;
    int base = b * SCAN_CHUNK;
    int s = 0;
    for (int i = 0; i < 4; ++i) {
        int idx = base + t + i * 256;
        if (idx < N_NODES) s += deg[idx];
    }
    for (int off = 32; off; off >>= 1) s += __shfl_down(s, off);
    if ((t & 63) == 0) sm[t >> 6] = s;
    __syncthreads();
    if (t == 0) bsum[b] = sm[0] + sm[1] + sm[2] + sm[3];
}

__global__ void k_scan_bsum(const int* __restrict__ bsum, int* __restrict__ bscan) {
    if (threadIdx.x == 0) {
        int r = 0;
        for (int i = 0; i < NBLK; ++i) { bscan[i] = r; r += bsum[i]; }
    }
}

__global__ void k_scan_final(const int* __restrict__ deg, const int* __restrict__ bscan,
                             int* __restrict__ offsets, int* __restrict__ cursor) {
    __shared__ int sm[256];
    int b = blockIdx.x, t = threadIdx.x;
    int base = b * SCAN_CHUNK + t * 4;
    int c[4];
    for (int e = 0; e < 4; ++e) {
        int idx = base + e;
        c[e] = (idx < N_NODES) ? deg[idx] : 0;
    }
    int s = c[0] + c[1] + c[2] + c[3];
    sm[t] = s;
    __syncthreads();
    for (int off = 1; off < 256; off <<= 1) {
        int v = (t >= off) ? sm[t - off] : 0;
        __syncthreads();
        sm[t] += v;
        __syncthreads();
    }
    int run = sm[t] - s + bscan[b];
    for (int e = 0; e < 4; ++e) {
        int idx = base + e;
        if (idx < N_NODES) { offsets[idx] = run; cursor[idx] = run; }
        run += c[e];
    }
}

__global__ void k_fill(const int* __restrict__ src, const int* __restrict__ dst,
                       int* __restrict__ cursor, int* __restrict__ csr) {
    int e = blockIdx.x * 256 + threadIdx.x;
    if (e < N_EDGES) {
        int d = dst[e];
        int pos = atomicAdd(&cursor[d], 1);
        csr[pos] = src[e];
    }
}

// ---------------- fp32 -> fp16 convert (8 elems/thread) ----------------
__global__ void k_tohalf(const float* __restrict__ in, half_t* __restrict__ out, int n8) {
    int i = blockIdx.x * 256 + threadIdx.x;
    if (i < n8) {
        float4 a = *reinterpret_cast<const float4*>(in + (size_t)i * 8);
        float4 b = *reinterpret_cast<const float4*>(in + (size_t)i * 8 + 4);
        f16x8 h;
        h[0] = (half_t)a.x; h[1] = (half_t)a.y; h[2] = (half_t)a.z; h[3] = (half_t)a.w;
        h[4] = (half_t)b.x; h[5] = (half_t)b.y; h[6] = (half_t)b.z; h[7] = (half_t)b.w;
        *reinterpret_cast<f16x8*>(out + (size_t)i * 8) = h;
    }
}

// ---------------- mean aggregation -> fp16 hi/lo planes --------------------
__global__ __launch_bounds__(256) void k_aggregate_h(
    const half_t* __restrict__ xh, const int* __restrict__ offsets,
    const int* __restrict__ deg, const int* __restrict__ csr,
    half_t* __restrict__ aggH, half_t* __restrict__ aggL) {
    int wave = threadIdx.x >> 6;
    int lane = threadIdx.x & 63;
    int node = blockIdx.x * 4 + wave;
    int off = offsets[node];
    int dg = deg[node];
    const size_t lo4 = (size_t)lane * 4;
    float4 a0 = {0.f, 0.f, 0.f, 0.f}, a1 = a0, a2 = a0, a3 = a0;
    int j = 0;
    for (; j + 4 <= dg; j += 4) {
        int s0 = csr[off + j + 0];
        int s1 = csr[off + j + 1];
        int s2 = csr[off + j + 2];
        int s3 = csr[off + j + 3];
        f16x4 v0 = *reinterpret_cast<const f16x4*>(xh + (size_t)s0 * HID + lo4);
        f16x4 v1 = *reinterpret_cast<const f16x4*>(xh + (size_t)s1 * HID + lo4);
        f16x4 v2 = *reinterpret_cast<const f16x4*>(xh + (size_t)s2 * HID + lo4);
        f16x4 v3 = *reinterpret_cast<const f16x4*>(xh + (size_t)s3 * HID + lo4);
        a0.x += (float)v0[0]; a0.y += (float)v0[1]; a0.z += (float)v0[2]; a0.w += (float)v0[3];
        a1.x += (float)v1[0]; a1.y += (float)v1[1]; a1.z += (float)v1[2]; a1.w += (float)v1[3];
        a2.x += (float)v2[0]; a2.y += (float)v2[1]; a2.z += (float)v2[2]; a2.w += (float)v2[3];
        a3.x += (float)v3[0]; a3.y += (float)v3[1]; a3.z += (float)v3[2]; a3.w += (float)v3[3];
    }
    for (; j < dg; ++j) {
        int s = csr[off + j];
        f16x4 v = *reinterpret_cast<const f16x4*>(xh + (size_t)s * HID + lo4);
        a0.x += (float)v[0]; a0.y += (float)v[1]; a0.z += (float)v[2]; a0.w += (float)v[3];
    }
    float av[4];
    av[0] = (a0.x + a1.x) + (a2.x + a3.x);
    av[1] = (a0.y + a1.y) + (a2.y + a3.y);
    av[2] = (a0.z + a1.z) + (a2.z + a3.z);
    av[3] = (a0.w + a1.w) + (a2.w + a3.w);
    float inv = 1.0f / (float)(dg > 0 ? dg : 1);
    f16x4 hi, lo;
#pragma unroll
    for (int c = 0; c < 4; ++c) {
        float v = av[c] * inv;
        half_t h = (half_t)v;
        hi[c] = h;
        lo[c] = (half_t)(v - (float)h);
    }
    *reinterpret_cast<f16x4*>(aggH + (size_t)node * HID + lo4) = hi;
    *reinterpret_cast<f16x4*>(aggL + (size_t)node * HID + lo4) = lo;
}

// ---------------- weight split+transpose: hi[col][k] then lo[col][k] -------
__global__ void k_splitw(const float* __restrict__ W, half_t* __restrict__ out, int ncols) {
    int col = blockIdx.x;
    int k = threadIdx.x;
    float v = W[(size_t)k * ncols + col];
    half_t h = (half_t)v;
    out[(size_t)col * 256 + k] = h;
    out[(size_t)ncols * 256 + (size_t)col * 256 + k] = (half_t)(v - (float)h);
}

// ---------------- barrier-free direct-fragment MFMA GEMM -------------------
// C[M][BN] = relu?(bias + A1@B1 [+ A2@B2]); K=256.
// A1: fp16 hi (+ lo plane if A1LO). A2: fp16 exact. B: pre-split hi|lo,
// transposed [col][k]. All operands loaded as MFMA fragments DIRECTLY from
// global (16B per lane) -- no LDS, no __syncthreads, each wave independent.
// Tile 128 x BN (8 waves, wm 0..1 x wn 0..3). Full-width BN => in-place
// C==A2 race-free (stores happen after all reads, own rows only).
template <int BN, bool A1LO, bool HASA2, bool OUTH>
__global__ __launch_bounds__(512, 3) void k_gemm_nb(
    const half_t* __restrict__ A1h, const half_t* __restrict__ A1l,
    const half_t* __restrict__ B1,
    const half_t* __restrict__ A2h, const half_t* __restrict__ B2,
    const float* __restrict__ bias, void* Cv, int M, int doRelu) {
    constexpr int WNW = BN / 4;   // wave tile width
    constexpr int NF = WNW / 16;  // n-fragments per wave
    const int tid = threadIdx.x;
    const int lane = tid & 63;
    const int m0 = blockIdx.x * 128;
    const int l16 = lane & 15, fkg = lane >> 4;
    const int wid = tid >> 6, wm = wid >> 2, wn = wid & 3;
    const int kbase = fkg * 8;

    int grows[4];
#pragma unroll
    for (int mf = 0; mf < 4; ++mf) {
        int r = m0 + wm * 64 + mf * 16 + l16;
        grows[mf] = r < M ? r : M - 1;
    }

    f32x4 acc[4][NF] = {};

    // ---- op0: A1 @ B1 (3 passes if A1LO else 2) ----
    for (int s = 0; s < 8; ++s) {
        const int kk = s * 32 + kbase;
        f16x8 ah[4], al[4];
#pragma unroll
        for (int mf = 0; mf < 4; ++mf) {
            ah[mf] = *reinterpret_cast<const f16x8*>(A1h + (size_t)grows[mf] * 256 + kk);
            if (A1LO)
                al[mf] = *reinterpret_cast<const f16x8*>(A1l + (size_t)grows[mf] * 256 + kk);
        }
#pragma unroll
        for (int nf = 0; nf < NF; ++nf) {
            const size_t bo = (size_t)(wn * WNW + nf * 16 + l16) * 256 + kk;
            f16x8 bh = *reinterpret_cast<const f16x8*>(B1 + bo);
            f16x8 bl = *reinterpret_cast<const f16x8*>(B1 + (size_t)BN * 256 + bo);
#pragma unroll
            for (int mf = 0; mf < 4; ++mf)
                acc[mf][nf] = __builtin_amdgcn_mfma_f32_16x16x32_f16(ah[mf], bh, acc[mf][nf], 0, 0, 0);
            if (A1LO) {
#pragma unroll
                for (int mf = 0; mf < 4; ++mf)
                    acc[mf][nf] = __builtin_amdgcn_mfma_f32_16x16x32_f16(al[mf], bh, acc[mf][nf], 0, 0, 0);
            }
#pragma unroll
            for (int mf = 0; mf < 4; ++mf)
                acc[mf][nf] = __builtin_amdgcn_mfma_f32_16x16x32_f16(ah[mf], bl, acc[mf][nf], 0, 0, 0);
        }
    }

    // ---- op1: A2 @ B2 (2 passes, A exact fp16) ----
    if constexpr (HASA2) {
        for (int s = 0; s < 8; ++s) {
            const int kk = s * 32 + kbase;
            f16x8 ah[4];
#pragma unroll
            for (int mf = 0; mf < 4; ++mf)
                ah[mf] = *reinterpret_cast<const f16x8*>(A2h + (size_t)grows[mf] * 256 + kk);
#pragma unroll
            for (int nf = 0; nf < NF; ++nf) {
                const size_t bo = (size_t)(wn * WNW + nf * 16 + l16) * 256 + kk;
                f16x8 bh = *reinterpret_cast<const f16x8*>(B2 + bo);
                f16x8 bl = *reinterpret_cast<const f16x8*>(B2 + (size_t)BN * 256 + bo);
#pragma unroll
                for (int mf = 0; mf < 4; ++mf)
                    acc[mf][nf] = __builtin_amdgcn_mfma_f32_16x16x32_f16(ah[mf], bh, acc[mf][nf], 0, 0, 0);
#pragma unroll
                for (int mf = 0; mf < 4; ++mf)
                    acc[mf][nf] = __builtin_amdgcn_mfma_f32_16x16x32_f16(ah[mf], bl, acc[mf][nf], 0, 0, 0);
            }
        }
    }

    // epilogue: row = wm*64+mf*16+(lane>>4)*4+r, col = wn*WNW+nf*16+l16
#pragma unroll
    for (int mf = 0; mf < 4; ++mf) {
        int row = m0 + wm * 64 + mf * 16 + (lane >> 4) * 4;
#pragma unroll
        for (int nf = 0; nf < NF; ++nf) {
            int col = wn * WNW + nf * 16 + l16;
            float bv = bias[col];
#pragma unroll
            for (int r = 0; r < 4; ++r) {
                int gr = row + r;
                if (gr < M) {
                    float v = acc[mf][nf][r] + bv;
                    if (doRelu) v = fmaxf(v, 0.f);
                    if (OUTH)
                        ((half_t*)Cv)[(size_t)gr * BN + col] = (half_t)v;
                    else
                        ((float*)Cv)[(size_t)gr * BN + col] = v;
                }
            }
        }
    }
}

// ---------------- head: out = h @ W2 + b2   (128 -> 4) ----------------
__global__ void k_head(const float* __restrict__ h, const float* __restrict__ W2,
                       const float* __restrict__ b2, float* __restrict__ out) {
    int wave = threadIdx.x >> 6, lane = threadIdx.x & 63;
    int node = blockIdx.x * 4 + wave;
    const float* hr = h + (size_t)node * 128;
    float p0 = 0.f, p1 = 0.f, p2 = 0.f, p3 = 0.f;
    for (int j = lane; j < 128; j += 64) {
        float hv = hr[j];
        p0 += hv * W2[j * 4 + 0];
        p1 += hv * W2[j * 4 + 1];
        p2 += hv * W2[j * 4 + 2];
        p3 += hv * W2[j * 4 + 3];
    }
    for (int off = 32; off; off >>= 1) {
        p0 += __shfl_down(p0, off);
        p1 += __shfl_down(p1, off);
        p2 += __shfl_down(p2, off);
        p3 += __shfl_down(p3, off);
    }
    if (lane == 0) {
        float4 o = {p0 + b2[0], p1 + b2[1], p2 + b2[2], p3 + b2[3]};
        *reinterpret_cast<float4*>(out + (size_t)node * 4) = o;
    }
}

extern "C" void kernel_launch(void* const* d_in, const int* in_sizes, int n_in,
                              void* d_out, int out_size, void* d_ws, size_t ws_size,
                              hipStream_t stream) {
    const float* x  = (const float*)d_in[0];
    const int*   ei = (const int*)d_in[1];
    const float* Wl = (const float*)d_in[2];
    const float* bl = (const float*)d_in[3];
    const float* Wr = (const float*)d_in[4];
    const float* W1 = (const float*)d_in[5];
    const float* b1 = (const float*)d_in[6];
    const float* W2 = (const float*)d_in[7];
    const float* b2 = (const float*)d_in[8];
    float* out = (float*)d_out;

    char* w = (char*)d_ws;
    size_t o = 0;
    auto alloc = [&](size_t bytes) -> void* {
        void* p = w + o;
        o += (bytes + 255) & ~(size_t)255;
        return p;
    };
    int* deg     = (int*)alloc((size_t)N_NODES * 4);
    int* cursor  = (int*)alloc((size_t)N_NODES * 4);
    int* offsets = (int*)alloc((size_t)N_NODES * 4);
    int* bsum    = (int*)alloc((size_t)NBLK * 4);
    int* bscan   = (int*)alloc((size_t)NBLK * 4);
    int* csr     = (int*)alloc((size_t)N_EDGES * 4);
    half_t* aggH = (half_t*)alloc((size_t)N_NODES * HID * 2);
    half_t* aggL = (half_t*)alloc((size_t)N_NODES * HID * 2);
    half_t* xh   = (half_t*)alloc((size_t)N_NODES * HID * 2);
    half_t* WlT[3]; half_t* WrT[3];
    for (int l = 0; l < 3; ++l) {
        WlT[l] = (half_t*)alloc((size_t)256 * 256 * 2 * 2);
        WrT[l] = (half_t*)alloc((size_t)256 * 256 * 2 * 2);
    }
    half_t* W1T = (half_t*)alloc((size_t)128 * 256 * 2 * 2);
    float* h = (float*)aggL;  // aggL dead after last layer GEMM; same size

    const int* srcA = ei;
    const int* dstA = ei + N_EDGES;

    for (int l = 0; l < 3; ++l) {
        k_splitw<<<256, 256, 0, stream>>>(Wl + (size_t)l * 65536, WlT[l], 256);
        k_splitw<<<256, 256, 0, stream>>>(Wr + (size_t)l * 65536, WrT[l], 256);
    }
    k_splitw<<<128, 256, 0, stream>>>(W1, W1T, 128);
    k_tohalf<<<(N_NODES * HID / 8 + 255) / 256, 256, 0, stream>>>(x, xh, N_NODES * HID / 8);

    hipMemsetAsync(deg, 0, (size_t)N_NODES * 4, stream);
    k_count<<<(N_EDGES + 255) / 256, 256, 0, stream>>>(dstA, deg);
    k_blocksum<<<NBLK, 256, 0, stream>>>(deg, bsum);
    k_scan_bsum<<<1, 64, 0, stream>>>(bsum, bscan);
    k_scan_final<<<NBLK, 256, 0, stream>>>(deg, bscan, offsets, cursor);
    k_fill<<<(N_EDGES + 255) / 256, 256, 0, stream>>>(srcA, dstA, cursor, csr);

    const int mblocks = (N_NODES + 127) / 128;
    for (int l = 0; l < 3; ++l) {
        k_aggregate_h<<<N_NODES / 4, 256, 0, stream>>>(xh, offsets, deg, csr, aggH, aggL);
        // feat(fp16, in-place xh) = relu(bl + agg@Wl + feat@Wr)
        k_gemm_nb<256, true, true, true><<<mblocks, 512, 0, stream>>>(
            aggH, aggL, WlT[l], xh, WrT[l], bl + (size_t)l * 256, xh, N_NODES, 1);
    }
    // h(fp32) = relu(feat@W1 + b1)
    k_gemm_nb<128, false, false, false><<<mblocks, 512, 0, stream>>>(
        xh, nullptr, W1T, nullptr, nullptr, b1, h, N_NODES, 1);
    k_head<<<N_NODES / 4, 256, 0, stream>>>(h, W2, b2, out);
}

// Round 7
// 1220.741 us; speedup vs baseline: 1.1269x; 1.1269x over previous
//
#include <hip/hip_runtime.h>

#define N_NODES 100000
#define N_EDGES 1600000
#define HID 256

typedef _Float16 half_t;
using f16x8 = __attribute__((ext_vector_type(8))) half_t;
using f16x4 = __attribute__((ext_vector_type(4))) half_t;
using f32x4 = __attribute__((ext_vector_type(4))) float;

constexpr int SCAN_CHUNK = 1024;
constexpr int NBLK = (N_NODES + SCAN_CHUNK - 1) / SCAN_CHUNK; // 98

#define GLOAD_LDS16(gp, lp)                                                    \
    __builtin_amdgcn_global_load_lds(                                         \
        (const __attribute__((address_space(1))) void*)(gp),                  \
        (__attribute__((address_space(3))) void*)(lp), 16, 0, 0)

template <int N>
__device__ __forceinline__ void vmwait() {
    asm volatile("s_waitcnt vmcnt(%0)" :: "n"(N) : "memory");
}

// ---------------- CSR build ----------------
__global__ void k_count(const int* __restrict__ dst, int* __restrict__ deg) {
    int e = blockIdx.x * 256 + threadIdx.x;
    if (e < N_EDGES) atomicAdd(&deg[dst[e]], 1);
}

__global__ void k_blocksum(const int* __restrict__ deg, int* __restrict__ bsum) {
    __shared__ int sm[4];
    int b = blockIdx.x, t = threadIdx.x;
    int base = b * SCAN_CHUNK;
    int s = 0;
    for (int i = 0; i < 4; ++i) {
        int idx = base + t + i * 256;
        if (idx < N_NODES) s += deg[idx];
    }
    for (int off = 32; off; off >>= 1) s += __shfl_down(s, off);
    if ((t & 63) == 0) sm[t >> 6] = s;
    __syncthreads();
    if (t == 0) bsum[b] = sm[0] + sm[1] + sm[2] + sm[3];
}

__global__ void k_scan_bsum(const int* __restrict__ bsum, int* __restrict__ bscan) {
    if (threadIdx.x == 0) {
        int r = 0;
        for (int i = 0; i < NBLK; ++i) { bscan[i] = r; r += bsum[i]; }
    }
}

__global__ void k_scan_final(const int* __restrict__ deg, const int* __restrict__ bscan,
                             int* __restrict__ offsets, int* __restrict__ cursor) {
    __shared__ int sm[256];
    int b = blockIdx.x, t = threadIdx.x;
    int base = b * SCAN_CHUNK + t * 4;
    int c[4];
    for (int e = 0; e < 4; ++e) {
        int idx = base + e;
        c[e] = (idx < N_NODES) ? deg[idx] : 0;
    }
    int s = c[0] + c[1] + c[2] + c[3];
    sm[t] = s;
    __syncthreads();
    for (int off = 1; off < 256; off <<= 1) {
        int v = (t >= off) ? sm[t - off] : 0;
        __syncthreads();
        sm[t] += v;
        __syncthreads();
    }
    int run = sm[t] - s + bscan[b];
    for (int e = 0; e < 4; ++e) {
        int idx = base + e;
        if (idx < N_NODES) { offsets[idx] = run; cursor[idx] = run; }
        run += c[e];
    }
}

__global__ void k_fill(const int* __restrict__ src, const int* __restrict__ dst,
                       int* __restrict__ cursor, int* __restrict__ csr) {
    int e = blockIdx.x * 256 + threadIdx.x;
    if (e < N_EDGES) {
        int d = dst[e];
        int pos = atomicAdd(&cursor[d], 1);
        csr[pos] = src[e];
    }
}

// ---------------- fp32 -> fp16 convert ----------------
__global__ void k_tohalf(const float* __restrict__ in, half_t* __restrict__ out, int n8) {
    int i = blockIdx.x * 256 + threadIdx.x;
    if (i < n8) {
        float4 a = *reinterpret_cast<const float4*>(in + (size_t)i * 8);
        float4 b = *reinterpret_cast<const float4*>(in + (size_t)i * 8 + 4);
        f16x8 h;
        h[0] = (half_t)a.x; h[1] = (half_t)a.y; h[2] = (half_t)a.z; h[3] = (half_t)a.w;
        h[4] = (half_t)b.x; h[5] = (half_t)b.y; h[6] = (half_t)b.z; h[7] = (half_t)b.w;
        *reinterpret_cast<f16x8*>(out + (size_t)i * 8) = h;
    }
}

// ---------------- mean aggregation -> fp16 hi/lo planes --------------------
__global__ __launch_bounds__(256) void k_aggregate_h(
    const half_t* __restrict__ xh, const int* __restrict__ offsets,
    const int* __restrict__ deg, const int* __restrict__ csr,
    half_t* __restrict__ aggH, half_t* __restrict__ aggL) {
    int wave = threadIdx.x >> 6;
    int lane = threadIdx.x & 63;
    int node = blockIdx.x * 4 + wave;
    int off = offsets[node];
    int dg = deg[node];
    const size_t lo4 = (size_t)lane * 4;
    float4 a0 = {0.f, 0.f, 0.f, 0.f}, a1 = a0, a2 = a0, a3 = a0;
    int j = 0;
    for (; j + 4 <= dg; j += 4) {
        int s0 = csr[off + j + 0];
        int s1 = csr[off + j + 1];
        int s2 = csr[off + j + 2];
        int s3 = csr[off + j + 3];
        f16x4 v0 = *reinterpret_cast<const f16x4*>(xh + (size_t)s0 * HID + lo4);
        f16x4 v1 = *reinterpret_cast<const f16x4*>(xh + (size_t)s1 * HID + lo4);
        f16x4 v2 = *reinterpret_cast<const f16x4*>(xh + (size_t)s2 * HID + lo4);
        f16x4 v3 = *reinterpret_cast<const f16x4*>(xh + (size_t)s3 * HID + lo4);
        a0.x += (float)v0[0]; a0.y += (float)v0[1]; a0.z += (float)v0[2]; a0.w += (float)v0[3];
        a1.x += (float)v1[0]; a1.y += (float)v1[1]; a1.z += (float)v1[2]; a1.w += (float)v1[3];
        a2.x += (float)v2[0]; a2.y += (float)v2[1]; a2.z += (float)v2[2]; a2.w += (float)v2[3];
        a3.x += (float)v3[0]; a3.y += (float)v3[1]; a3.z += (float)v3[2]; a3.w += (float)v3[3];
    }
    for (; j < dg; ++j) {
        int s = csr[off + j];
        f16x4 v = *reinterpret_cast<const f16x4*>(xh + (size_t)s * HID + lo4);
        a0.x += (float)v[0]; a0.y += (float)v[1]; a0.z += (float)v[2]; a0.w += (float)v[3];
    }
    float av[4];
    av[0] = (a0.x + a1.x) + (a2.x + a3.x);
    av[1] = (a0.y + a1.y) + (a2.y + a3.y);
    av[2] = (a0.z + a1.z) + (a2.z + a3.z);
    av[3] = (a0.w + a1.w) + (a2.w + a3.w);
    float inv = 1.0f / (float)(dg > 0 ? dg : 1);
    f16x4 hi, lo;
#pragma unroll
    for (int c = 0; c < 4; ++c) {
        float v = av[c] * inv;
        half_t h = (half_t)v;
        hi[c] = h;
        lo[c] = (half_t)(v - (float)h);
    }
    *reinterpret_cast<f16x4*>(aggH + (size_t)node * HID + lo4) = hi;
    *reinterpret_cast<f16x4*>(aggL + (size_t)node * HID + lo4) = lo;
}

// ---------------- weight split+transpose: hi[col][k] then lo[col][k] -------
__global__ void k_splitw(const float* __restrict__ W, half_t* __restrict__ out, int ncols) {
    int col = blockIdx.x;
    int k = threadIdx.x;
    float v = W[(size_t)k * ncols + col];
    half_t h = (half_t)v;
    out[(size_t)col * 256 + k] = h;
    out[(size_t)ncols * 256 + (size_t)col * 256 + k] = (half_t)(v - (float)h);
}

// ---------------- pipelined MFMA GEMM (3-buf LDS, counted vmcnt) -----------
// C[M][BN] = relu?(bias + A1@B1 [+ A2@B2]); K=256 per op.
// A planes fp16 [row][256] (hi + optional lo). B pre-split hi|lo, [col][k].
// Tile 128 x BN, 8 waves. Steps: (HASA2?2:1) ops x 8 K-slices of 32.
// Pipeline: prefetch depth 2, raw s_barrier + counted vmcnt (never 0 mid-loop).
template <int BN, bool A1LO, bool HASA2, bool OUTH>
__global__ __launch_bounds__(512, 2) void k_gemm_pipe(
    const half_t* __restrict__ A1h, const half_t* __restrict__ A1l,
    const half_t* __restrict__ B1,
    const half_t* __restrict__ A2h, const half_t* __restrict__ B2,
    const float* __restrict__ bias, void* Cv, int M, int doRelu) {
    constexpr int WNW = BN / 4;
    constexpr int NF = WNW / 16;
    constexpr int NSTEPS = HASA2 ? 16 : 8;
    constexpr int BL = BN / 64;                 // B gloads per thread per stage
    constexpr int LPS0 = BL + (A1LO ? 2 : 1);   // loads/thread, op0 stage
    constexpr int LPS1 = BL + 1;                // loads/thread, op1 stage

    __shared__ f16x8 sA[3][512];                   // A hi: [kg*128+row]
    __shared__ f16x8 sAl[A1LO ? 3 : 1][512];       // A lo
    __shared__ f16x8 sB[3][8 * BN];                // B hi: [0,4BN), lo: [4BN,8BN)

    const int tid = threadIdx.x;
    const int lane = tid & 63;
    const int m0 = blockIdx.x * 128;
    const int skg = tid >> 7;
    const int srow = tid & 127;
    const int grow = min(m0 + srow, M - 1);
    const int l16 = lane & 15, fkg = lane >> 4;
    const int wid = tid >> 6, wm = wid >> 2, wn = wid & 3;
    const int aBase = fkg * 128 + wm * 64 + l16;
    const int bBase = fkg * BN + wn * WNW + l16;

    f32x4 acc[4][NF] = {};

    auto STAGE = [&](int s, int buf) {
        const int op = HASA2 ? (s >> 3) : 0;
        const int kk = (s & 7) * 32;
        const half_t* Bp = (HASA2 && op) ? B2 : B1;
#pragma unroll
        for (int b = 0; b < BN / 128; ++b) {
            int c = tid + b * 512;
            int col = c & (BN - 1);
            int ckg = (BN == 256) ? (c >> 8) : (c >> 7);
            const half_t* bh = Bp + (size_t)col * 256 + kk + ckg * 8;
            GLOAD_LDS16(bh, &sB[buf][c]);
            GLOAD_LDS16(bh + (size_t)BN * 256, &sB[buf][4 * BN + c]);
        }
        const half_t* Ahp = (HASA2 && op) ? A2h : A1h;
        GLOAD_LDS16(Ahp + (size_t)grow * 256 + kk + skg * 8, &sA[buf][tid]);
        if (A1LO && op == 0)
            GLOAD_LDS16(A1l + (size_t)grow * 256 + kk + skg * 8, &sAl[buf][tid]);
    };

    // prologue: stages 0,1 in flight
    STAGE(0, 0);
    STAGE(1, 1);

    int cb = 0;
    for (int s = 0; s < NSTEPS; ++s) {
        // wait for stage s (allow stage s+1 to stay in flight)
        if (s == NSTEPS - 1) vmwait<0>();
        else if (HASA2 && s >= 7) vmwait<LPS1>();
        else vmwait<LPS0>();
        __builtin_amdgcn_s_barrier();       // all waves' stage-s loads landed;
                                            // all waves done computing s-1
        __builtin_amdgcn_sched_barrier(0);  // no hoisting above the barrier
        if (s + 2 < NSTEPS) {
            int pb = cb + 2; if (pb >= 3) pb -= 3;
            STAGE(s + 2, pb);
        }
        // compute step s from buf cb
        {
            const int op = HASA2 ? (s >> 3) : 0;
            const bool useLo = A1LO && op == 0;
            f16x8 ah[4], al[4];
#pragma unroll
            for (int mf = 0; mf < 4; ++mf) {
                ah[mf] = sA[cb][aBase + mf * 16];
                if (useLo) al[mf] = sAl[cb][aBase + mf * 16];
            }
#pragma unroll
            for (int nf = 0; nf < NF; ++nf) {
                f16x8 bh = sB[cb][bBase + nf * 16];
                f16x8 bl = sB[cb][4 * BN + bBase + nf * 16];
#pragma unroll
                for (int mf = 0; mf < 4; ++mf) {
                    acc[mf][nf] = __builtin_amdgcn_mfma_f32_16x16x32_f16(ah[mf], bh, acc[mf][nf], 0, 0, 0);
                    if (useLo)
                        acc[mf][nf] = __builtin_amdgcn_mfma_f32_16x16x32_f16(al[mf], bh, acc[mf][nf], 0, 0, 0);
                    acc[mf][nf] = __builtin_amdgcn_mfma_f32_16x16x32_f16(ah[mf], bl, acc[mf][nf], 0, 0, 0);
                }
            }
        }
        cb = (cb == 2) ? 0 : cb + 1;
    }

    // epilogue: row = wm*64+mf*16+(lane>>4)*4+r, col = wn*WNW+nf*16+l16
#pragma unroll
    for (int mf = 0; mf < 4; ++mf) {
        int row = m0 + wm * 64 + mf * 16 + (lane >> 4) * 4;
#pragma unroll
        for (int nf = 0; nf < NF; ++nf) {
            int col = wn * WNW + nf * 16 + l16;
            float bv = bias[col];
#pragma unroll
            for (int r = 0; r < 4; ++r) {
                int gr = row + r;
                if (gr < M) {
                    float v = acc[mf][nf][r] + bv;
                    if (doRelu) v = fmaxf(v, 0.f);
                    if (OUTH)
                        ((half_t*)Cv)[(size_t)gr * BN + col] = (half_t)v;
                    else
                        ((float*)Cv)[(size_t)gr * BN + col] = v;
                }
            }
        }
    }
}

// ---------------- head: out = h @ W2 + b2   (128 -> 4) ----------------
__global__ void k_head(const float* __restrict__ h, const float* __restrict__ W2,
                       const float* __restrict__ b2, float* __restrict__ out) {
    int wave = threadIdx.x >> 6, lane = threadIdx.x & 63;
    int node = blockIdx.x * 4 + wave;
    const float* hr = h + (size_t)node * 128;
    float p0 = 0.f, p1 = 0.f, p2 = 0.f, p3 = 0.f;
    for (int j = lane; j < 128; j += 64) {
        float hv = hr[j];
        p0 += hv * W2[j * 4 + 0];
        p1 += hv * W2[j * 4 + 1];
        p2 += hv * W2[j * 4 + 2];
        p3 += hv * W2[j * 4 + 3];
    }
    for (int off = 32; off; off >>= 1) {
        p0 += __shfl_down(p0, off);
        p1 += __shfl_down(p1, off);
        p2 += __shfl_down(p2, off);
        p3 += __shfl_down(p3, off);
    }
    if (lane == 0) {
        float4 o = {p0 + b2[0], p1 + b2[1], p2 + b2[2], p3 + b2[3]};
        *reinterpret_cast<float4*>(out + (size_t)node * 4) = o;
    }
}

extern "C" void kernel_launch(void* const* d_in, const int* in_sizes, int n_in,
                              void* d_out, int out_size, void* d_ws, size_t ws_size,
                              hipStream_t stream) {
    const float* x  = (const float*)d_in[0];
    const int*   ei = (const int*)d_in[1];
    const float* Wl = (const float*)d_in[2];
    const float* bl = (const float*)d_in[3];
    const float* Wr = (const float*)d_in[4];
    const float* W1 = (const float*)d_in[5];
    const float* b1 = (const float*)d_in[6];
    const float* W2 = (const float*)d_in[7];
    const float* b2 = (const float*)d_in[8];
    float* out = (float*)d_out;

    char* w = (char*)d_ws;
    size_t o = 0;
    auto alloc = [&](size_t bytes) -> void* {
        void* p = w + o;
        o += (bytes + 255) & ~(size_t)255;
        return p;
    };
    int* deg     = (int*)alloc((size_t)N_NODES * 4);
    int* cursor  = (int*)alloc((size_t)N_NODES * 4);
    int* offsets = (int*)alloc((size_t)N_NODES * 4);
    int* bsum    = (int*)alloc((size_t)NBLK * 4);
    int* bscan   = (int*)alloc((size_t)NBLK * 4);
    int* csr     = (int*)alloc((size_t)N_EDGES * 4);
    half_t* aggH = (half_t*)alloc((size_t)N_NODES * HID * 2);
    half_t* aggL = (half_t*)alloc((size_t)N_NODES * HID * 2);
    half_t* xh   = (half_t*)alloc((size_t)N_NODES * HID * 2);
    half_t* WlT[3]; half_t* WrT[3];
    for (int l = 0; l < 3; ++l) {
        WlT[l] = (half_t*)alloc((size_t)256 * 256 * 2 * 2);
        WrT[l] = (half_t*)alloc((size_t)256 * 256 * 2 * 2);
    }
    half_t* W1T = (half_t*)alloc((size_t)128 * 256 * 2 * 2);
    float* h = (float*)alloc((size_t)N_NODES * 128 * 4);

    const int* srcA = ei;
    const int* dstA = ei + N_EDGES;

    for (int l = 0; l < 3; ++l) {
        k_splitw<<<256, 256, 0, stream>>>(Wl + (size_t)l * 65536, WlT[l], 256);
        k_splitw<<<256, 256, 0, stream>>>(Wr + (size_t)l * 65536, WrT[l], 256);
    }
    k_splitw<<<128, 256, 0, stream>>>(W1, W1T, 128);
    k_tohalf<<<(N_NODES * HID / 8 + 255) / 256, 256, 0, stream>>>(x, xh, N_NODES * HID / 8);

    hipMemsetAsync(deg, 0, (size_t)N_NODES * 4, stream);
    k_count<<<(N_EDGES + 255) / 256, 256, 0, stream>>>(dstA, deg);
    k_blocksum<<<NBLK, 256, 0, stream>>>(deg, bsum);
    k_scan_bsum<<<1, 64, 0, stream>>>(bsum, bscan);
    k_scan_final<<<NBLK, 256, 0, stream>>>(deg, bscan, offsets, cursor);
    k_fill<<<(N_EDGES + 255) / 256, 256, 0, stream>>>(srcA, dstA, cursor, csr);

    const int mblocks = (N_NODES + 127) / 128;
    for (int l = 0; l < 3; ++l) {
        k_aggregate_h<<<N_NODES / 4, 256, 0, stream>>>(xh, offsets, deg, csr, aggH, aggL);
        // feat(fp16, in-place xh) = relu(bl + agg@Wl + feat@Wr)
        k_gemm_pipe<256, true, true, true><<<mblocks, 512, 0, stream>>>(
            aggH, aggL, WlT[l], xh, WrT[l], bl + (size_t)l * 256, xh, N_NODES, 1);
    }
    // h(fp32) = relu(feat@W1 + b1)
    k_gemm_pipe<128, false, false, false><<<mblocks, 512, 0, stream>>>(
        xh, nullptr, W1T, nullptr, nullptr, b1, h, N_NODES, 1);
    k_head<<<N_NODES / 4, 256, 0, stream>>>(h, W2, b2, out);
}

// Round 8
// 1072.403 us; speedup vs baseline: 1.2828x; 1.1383x over previous
//
#include <hip/hip_runtime.h>

#define N_NODES 100000
#define N_EDGES 1600000
#define HID 256

typedef _Float16 half_t;
using f16x8 = __attribute__((ext_vector_type(8))) half_t;
using f16x4 = __attribute__((ext_vector_type(4))) half_t;
using f32x4 = __attribute__((ext_vector_type(4))) float;

constexpr int SCAN_CHUNK = 1024;
constexpr int NBLK = (N_NODES + SCAN_CHUNK - 1) / SCAN_CHUNK; // 98

#define GLOAD_LDS16(gp, lp)                                                    \
    __builtin_amdgcn_global_load_lds(                                         \
        (const __attribute__((address_space(1))) void*)(gp),                  \
        (__attribute__((address_space(3))) void*)(lp), 16, 0, 0)

template <int N>
__device__ __forceinline__ void vmwait() {
    asm volatile("s_waitcnt vmcnt(%0)" :: "n"(N) : "memory");
}

// ---------------- CSR build ----------------
__global__ void k_count(const int* __restrict__ dst, int* __restrict__ deg) {
    int e = blockIdx.x * 256 + threadIdx.x;
    if (e < N_EDGES) atomicAdd(&deg[dst[e]], 1);
}

__global__ void k_blocksum(const int* __restrict__ deg, int* __restrict__ bsum) {
    __shared__ int sm[4];
    int b = blockIdx.x, t = threadIdx.x;
    int base = b * SCAN_CHUNK;
    int s = 0;
    for (int i = 0; i < 4; ++i) {
        int idx = base + t + i * 256;
        if (idx < N_NODES) s += deg[idx];
    }
    for (int off = 32; off; off >>= 1) s += __shfl_down(s, off);
    if ((t & 63) == 0) sm[t >> 6] = s;
    __syncthreads();
    if (t == 0) bsum[b] = sm[0] + sm[1] + sm[2] + sm[3];
}

__global__ void k_scan_bsum(const int* __restrict__ bsum, int* __restrict__ bscan) {
    if (threadIdx.x == 0) {
        int r = 0;
        for (int i = 0; i < NBLK; ++i) { bscan[i] = r; r += bsum[i]; }
    }
}

__global__ void k_scan_final(const int* __restrict__ deg, const int* __restrict__ bscan,
                             int* __restrict__ offsets, int* __restrict__ cursor) {
    __shared__ int sm[256];
    int b = blockIdx.x, t = threadIdx.x;
    int base = b * SCAN_CHUNK + t * 4;
    int c[4];
    for (int e = 0; e < 4; ++e) {
        int idx = base + e;
        c[e] = (idx < N_NODES) ? deg[idx] : 0;
    }
    int s = c[0] + c[1] + c[2] + c[3];
    sm[t] = s;
    __syncthreads();
    for (int off = 1; off < 256; off <<= 1) {
        int v = (t >= off) ? sm[t - off] : 0;
        __syncthreads();
        sm[t] += v;
        __syncthreads();
    }
    int run = sm[t] - s + bscan[b];
    for (int e = 0; e < 4; ++e) {
        int idx = base + e;
        if (idx < N_NODES) { offsets[idx] = run; cursor[idx] = run; }
        run += c[e];
    }
}

__global__ void k_fill(const int* __restrict__ src, const int* __restrict__ dst,
                       int* __restrict__ cursor, int* __restrict__ csr) {
    int e = blockIdx.x * 256 + threadIdx.x;
    if (e < N_EDGES) {
        int d = dst[e];
        int pos = atomicAdd(&cursor[d], 1);
        csr[pos] = src[e];
    }
}

// ---------------- fp32 -> fp16 convert ----------------
__global__ void k_tohalf(const float* __restrict__ in, half_t* __restrict__ out, int n8) {
    int i = blockIdx.x * 256 + threadIdx.x;
    if (i < n8) {
        float4 a = *reinterpret_cast<const float4*>(in + (size_t)i * 8);
        float4 b = *reinterpret_cast<const float4*>(in + (size_t)i * 8 + 4);
        f16x8 h;
        h[0] = (half_t)a.x; h[1] = (half_t)a.y; h[2] = (half_t)a.z; h[3] = (half_t)a.w;
        h[4] = (half_t)b.x; h[5] = (half_t)b.y; h[6] = (half_t)b.z; h[7] = (half_t)b.w;
        *reinterpret_cast<f16x8*>(out + (size_t)i * 8) = h;
    }
}

// ---------------- mean aggregation -> fp16 hi/lo planes --------------------
__global__ __launch_bounds__(256) void k_aggregate_h(
    const half_t* __restrict__ xh, const int* __restrict__ offsets,
    const int* __restrict__ deg, const int* __restrict__ csr,
    half_t* __restrict__ aggH, half_t* __restrict__ aggL) {
    int wave = threadIdx.x >> 6;
    int lane = threadIdx.x & 63;
    int node = blockIdx.x * 4 + wave;
    int off = offsets[node];
    int dg = deg[node];
    const size_t lo4 = (size_t)lane * 4;
    float4 a0 = {0.f, 0.f, 0.f, 0.f}, a1 = a0, a2 = a0, a3 = a0;
    int j = 0;
    for (; j + 4 <= dg; j += 4) {
        int s0 = csr[off + j + 0];
        int s1 = csr[off + j + 1];
        int s2 = csr[off + j + 2];
        int s3 = csr[off + j + 3];
        f16x4 v0 = *reinterpret_cast<const f16x4*>(xh + (size_t)s0 * HID + lo4);
        f16x4 v1 = *reinterpret_cast<const f16x4*>(xh + (size_t)s1 * HID + lo4);
        f16x4 v2 = *reinterpret_cast<const f16x4*>(xh + (size_t)s2 * HID + lo4);
        f16x4 v3 = *reinterpret_cast<const f16x4*>(xh + (size_t)s3 * HID + lo4);
        a0.x += (float)v0[0]; a0.y += (float)v0[1]; a0.z += (float)v0[2]; a0.w += (float)v0[3];
        a1.x += (float)v1[0]; a1.y += (float)v1[1]; a1.z += (float)v1[2]; a1.w += (float)v1[3];
        a2.x += (float)v2[0]; a2.y += (float)v2[1]; a2.z += (float)v2[2]; a2.w += (float)v2[3];
        a3.x += (float)v3[0]; a3.y += (float)v3[1]; a3.z += (float)v3[2]; a3.w += (float)v3[3];
    }
    for (; j < dg; ++j) {
        int s = csr[off + j];
        f16x4 v = *reinterpret_cast<const f16x4*>(xh + (size_t)s * HID + lo4);
        a0.x += (float)v[0]; a0.y += (float)v[1]; a0.z += (float)v[2]; a0.w += (float)v[3];
    }
    float av[4];
    av[0] = (a0.x + a1.x) + (a2.x + a3.x);
    av[1] = (a0.y + a1.y) + (a2.y + a3.y);
    av[2] = (a0.z + a1.z) + (a2.z + a3.z);
    av[3] = (a0.w + a1.w) + (a2.w + a3.w);
    float inv = 1.0f / (float)(dg > 0 ? dg : 1);
    f16x4 hi, lo;
#pragma unroll
    for (int c = 0; c < 4; ++c) {
        float v = av[c] * inv;
        half_t h = (half_t)v;
        hi[c] = h;
        lo[c] = (half_t)(v - (float)h);
    }
    *reinterpret_cast<f16x4*>(aggH + (size_t)node * HID + lo4) = hi;
    *reinterpret_cast<f16x4*>(aggL + (size_t)node * HID + lo4) = lo;
}

// ---------------- weight split+transpose: hi[col][k] then lo[col][k] -------
__global__ void k_splitw(const float* __restrict__ W, half_t* __restrict__ out, int ncols) {
    int col = blockIdx.x;
    int k = threadIdx.x;
    float v = W[(size_t)k * ncols + col];
    half_t h = (half_t)v;
    out[(size_t)col * 256 + k] = h;
    out[(size_t)ncols * 256 + (size_t)col * 256 + k] = (half_t)(v - (float)h);
}

// ---------------- double-buffered MFMA GEMM, counted vmcnt -----------------
// C[M][128*NSPLIT] = relu?(bias + A1@B1 [+ A2@B2]); K=256 per op.
// Tile 128 rows x 128 cols; grid = mtiles << LOGSPLIT (nb = low bits).
// Per step (k-slice 32): barrier; STAGE(t+1 -> buf^1); vmcnt(next LPS)
// [stage t+1 stays in flight]; barrier; MFMA(t, buf). Never vmcnt(0) mid-loop.
// LDS: 2 x (B 16KB + Ahi 8KB [+ Alo 8KB]) = 64/48 KB -> 2 blocks/CU.
template <bool A1LO, bool HASA2, bool OUTH, int LOGSPLIT>
__global__ __launch_bounds__(512, 4) void k_gemm_db(
    const half_t* __restrict__ A1h, const half_t* __restrict__ A1l,
    const half_t* __restrict__ B1, int B1loOff,
    const half_t* __restrict__ A2h,
    const half_t* __restrict__ B2, int B2loOff,
    const float* __restrict__ bias, void* Cv, int M, int doRelu) {
    constexpr int NSPLIT = 1 << LOGSPLIT;
    constexpr int NTOT = 128 * NSPLIT;
    constexpr int NSTEPS = HASA2 ? 16 : 8;

    __shared__ f16x8 sA[2][512];                 // A hi: [kg(4)][row(128)]
    __shared__ f16x8 sAl[A1LO ? 2 : 1][512];     // A lo
    __shared__ f16x8 sB[2][1024];                // hi: [0,512), lo: [512,1024); [kg][col]

    const int tid = threadIdx.x;
    const int lane = tid & 63;
    const int nb = blockIdx.x & (NSPLIT - 1);
    const int mt = blockIdx.x >> LOGSPLIT;
    const int m0 = mt * 128;
    const int col0 = nb * 128;
    const half_t* B1h_ = B1 + (size_t)col0 * 256;
    const half_t* B1l_ = B1 + B1loOff + (size_t)col0 * 256;
    const half_t* B2h_ = HASA2 ? B2 + (size_t)col0 * 256 : nullptr;
    const half_t* B2l_ = HASA2 ? B2 + B2loOff + (size_t)col0 * 256 : nullptr;
    const float* biasp = bias + col0;

    const int skg = tid >> 7;       // 0..3
    const int srow = tid & 127;
    const int grow = min(m0 + srow, M - 1);
    const int l16 = lane & 15, fkg = lane >> 4;
    const int wid = tid >> 6, wm = wid >> 2, wn = wid & 3;  // 2m x 4n
    const int aBase = fkg * 128 + wm * 64 + l16;
    const int bBase = fkg * 128 + wn * 32 + l16;

    f32x4 acc[4][2] = {};

    auto STAGE = [&](int s, int buf) {
        const int op = HASA2 ? (s >> 3) : 0;
        const int kk = (s & 7) * 32;
        const half_t* Bh = (HASA2 && op) ? B2h_ : B1h_;
        const half_t* Bl = (HASA2 && op) ? B2l_ : B1l_;
        const int colkg = (size_t)(tid & 127) * 256 + kk + (tid >> 7) * 8;
        GLOAD_LDS16(Bh + colkg, &sB[buf][tid]);
        GLOAD_LDS16(Bl + colkg, &sB[buf][512 + tid]);
        const half_t* Ah = (HASA2 && op) ? A2h : A1h;
        GLOAD_LDS16(Ah + (size_t)grow * 256 + kk + skg * 8, &sA[buf][tid]);
        if (A1LO && op == 0)
            GLOAD_LDS16(A1l + (size_t)grow * 256 + kk + skg * 8, &sAl[buf][tid]);
    };

    STAGE(0, 0);

#pragma unroll
    for (int t = 0; t < NSTEPS; ++t) {
        const int buf = t & 1;
        // barrier 1: all waves done computing t-1 (used buf^1) -> safe to restage it
        __builtin_amdgcn_s_barrier();
        __builtin_amdgcn_sched_barrier(0);
        if (t + 1 < NSTEPS) STAGE(t + 1, buf ^ 1);
        // wait for stage t (skip the just-issued stage t+1 loads)
        {
            const int s2 = t + 1;
            if (s2 >= NSTEPS) vmwait<0>();
            else if (A1LO && (!HASA2 || (s2 >> 3) == 0)) vmwait<4>();
            else vmwait<3>();
        }
        // barrier 2: everyone's stage-t loads landed
        __builtin_amdgcn_s_barrier();
        __builtin_amdgcn_sched_barrier(0);

        const int op = HASA2 ? (t >> 3) : 0;
        const bool useLo = A1LO && op == 0;
        f16x8 ah[4], al[4];
#pragma unroll
        for (int mf = 0; mf < 4; ++mf) {
            ah[mf] = sA[buf][aBase + mf * 16];
            if (useLo) al[mf] = sAl[buf][aBase + mf * 16];
        }
        __builtin_amdgcn_s_setprio(1);
#pragma unroll
        for (int nf = 0; nf < 2; ++nf) {
            f16x8 bh = sB[buf][bBase + nf * 16];
            f16x8 bl = sB[buf][512 + bBase + nf * 16];
#pragma unroll
            for (int mf = 0; mf < 4; ++mf) {
                acc[mf][nf] = __builtin_amdgcn_mfma_f32_16x16x32_f16(ah[mf], bh, acc[mf][nf], 0, 0, 0);
                if (useLo)
                    acc[mf][nf] = __builtin_amdgcn_mfma_f32_16x16x32_f16(al[mf], bh, acc[mf][nf], 0, 0, 0);
                acc[mf][nf] = __builtin_amdgcn_mfma_f32_16x16x32_f16(ah[mf], bl, acc[mf][nf], 0, 0, 0);
            }
        }
        __builtin_amdgcn_s_setprio(0);
    }

    // epilogue: row = m0+wm*64+mf*16+(lane>>4)*4+r, col = col0+wn*32+nf*16+l16
#pragma unroll
    for (int mf = 0; mf < 4; ++mf) {
        int row = m0 + wm * 64 + mf * 16 + (lane >> 4) * 4;
#pragma unroll
        for (int nf = 0; nf < 2; ++nf) {
            int col = wn * 32 + nf * 16 + l16;
            float bv = biasp[col];
#pragma unroll
            for (int r = 0; r < 4; ++r) {
                int gr = row + r;
                if (gr < M) {
                    float v = acc[mf][nf][r] + bv;
                    if (doRelu) v = fmaxf(v, 0.f);
                    if (OUTH)
                        ((half_t*)Cv)[(size_t)gr * NTOT + col0 + col] = (half_t)v;
                    else
                        ((float*)Cv)[(size_t)gr * NTOT + col0 + col] = v;
                }
            }
        }
    }
}

// ---------------- head: out = h @ W2 + b2   (128 -> 4) ----------------
__global__ void k_head(const float* __restrict__ h, const float* __restrict__ W2,
                       const float* __restrict__ b2, float* __restrict__ out) {
    int wave = threadIdx.x >> 6, lane = threadIdx.x & 63;
    int node = blockIdx.x * 4 + wave;
    const float* hr = h + (size_t)node * 128;
    float p0 = 0.f, p1 = 0.f, p2 = 0.f, p3 = 0.f;
    for (int j = lane; j < 128; j += 64) {
        float hv = hr[j];
        p0 += hv * W2[j * 4 + 0];
        p1 += hv * W2[j * 4 + 1];
        p2 += hv * W2[j * 4 + 2];
        p3 += hv * W2[j * 4 + 3];
    }
    for (int off = 32; off; off >>= 1) {
        p0 += __shfl_down(p0, off);
        p1 += __shfl_down(p1, off);
        p2 += __shfl_down(p2, off);
        p3 += __shfl_down(p3, off);
    }
    if (lane == 0) {
        float4 o = {p0 + b2[0], p1 + b2[1], p2 + b2[2], p3 + b2[3]};
        *reinterpret_cast<float4*>(out + (size_t)node * 4) = o;
    }
}

extern "C" void kernel_launch(void* const* d_in, const int* in_sizes, int n_in,
                              void* d_out, int out_size, void* d_ws, size_t ws_size,
                              hipStream_t stream) {
    const float* x  = (const float*)d_in[0];
    const int*   ei = (const int*)d_in[1];
    const float* Wl = (const float*)d_in[2];
    const float* bl = (const float*)d_in[3];
    const float* Wr = (const float*)d_in[4];
    const float* W1 = (const float*)d_in[5];
    const float* b1 = (const float*)d_in[6];
    const float* W2 = (const float*)d_in[7];
    const float* b2 = (const float*)d_in[8];
    float* out = (float*)d_out;

    char* w = (char*)d_ws;
    size_t o = 0;
    auto alloc = [&](size_t bytes) -> void* {
        void* p = w + o;
        o += (bytes + 255) & ~(size_t)255;
        return p;
    };
    int* deg     = (int*)alloc((size_t)N_NODES * 4);
    int* cursor  = (int*)alloc((size_t)N_NODES * 4);
    int* offsets = (int*)alloc((size_t)N_NODES * 4);
    int* bsum    = (int*)alloc((size_t)NBLK * 4);
    int* bscan   = (int*)alloc((size_t)NBLK * 4);
    int* csr     = (int*)alloc((size_t)N_EDGES * 4);
    half_t* aggH = (half_t*)alloc((size_t)N_NODES * HID * 2);
    half_t* aggL = (half_t*)alloc((size_t)N_NODES * HID * 2);
    half_t* xa   = (half_t*)alloc((size_t)N_NODES * HID * 2);
    half_t* xb   = (half_t*)alloc((size_t)N_NODES * HID * 2);
    half_t* WlT[3]; half_t* WrT[3];
    for (int l = 0; l < 3; ++l) {
        WlT[l] = (half_t*)alloc((size_t)256 * 256 * 2 * 2);
        WrT[l] = (half_t*)alloc((size_t)256 * 256 * 2 * 2);
    }
    half_t* W1T = (half_t*)alloc((size_t)128 * 256 * 2 * 2);
    float* h = (float*)aggH;  // aggH dead after layer-2 GEMM; 51.2MB fits h

    const int* srcA = ei;
    const int* dstA = ei + N_EDGES;

    for (int l = 0; l < 3; ++l) {
        k_splitw<<<256, 256, 0, stream>>>(Wl + (size_t)l * 65536, WlT[l], 256);
        k_splitw<<<256, 256, 0, stream>>>(Wr + (size_t)l * 65536, WrT[l], 256);
    }
    k_splitw<<<128, 256, 0, stream>>>(W1, W1T, 128);
    k_tohalf<<<(N_NODES * HID / 8 + 255) / 256, 256, 0, stream>>>(x, xa, N_NODES * HID / 8);

    hipMemsetAsync(deg, 0, (size_t)N_NODES * 4, stream);
    k_count<<<(N_EDGES + 255) / 256, 256, 0, stream>>>(dstA, deg);
    k_blocksum<<<NBLK, 256, 0, stream>>>(deg, bsum);
    k_scan_bsum<<<1, 64, 0, stream>>>(bsum, bscan);
    k_scan_final<<<NBLK, 256, 0, stream>>>(deg, bscan, offsets, cursor);
    k_fill<<<(N_EDGES + 255) / 256, 256, 0, stream>>>(srcA, dstA, cursor, csr);

    const int mtiles = (N_NODES + 127) / 128;  // 782
    half_t* cur = xa;
    half_t* nxt = xb;
    for (int l = 0; l < 3; ++l) {
        k_aggregate_h<<<N_NODES / 4, 256, 0, stream>>>(cur, offsets, deg, csr, aggH, aggL);
        // nxt(fp16) = relu(bl + agg@Wl + cur@Wr), N=256 split in 2 col-blocks
        k_gemm_db<true, true, true, 1><<<mtiles * 2, 512, 0, stream>>>(
            aggH, aggL, WlT[l], 65536, cur, WrT[l], 65536,
            bl + (size_t)l * 256, nxt, N_NODES, 1);
        half_t* tmp = cur; cur = nxt; nxt = tmp;
    }
    // h(fp32) = relu(cur@W1 + b1), N=128
    k_gemm_db<false, false, false, 0><<<mtiles, 512, 0, stream>>>(
        cur, nullptr, W1T, 32768, nullptr, nullptr, 0, b1, h, N_NODES, 1);
    k_head<<<N_NODES / 4, 256, 0, stream>>>(h, W2, b2, out);
}

// Round 9
// 876.111 us; speedup vs baseline: 1.5702x; 1.2240x over previous
//
#include <hip/hip_runtime.h>

#define N_NODES 100000
#define N_EDGES 1600000
#define HID 256

typedef _Float16 half_t;
using f16x8 = __attribute__((ext_vector_type(8))) half_t;
using f16x4 = __attribute__((ext_vector_type(4))) half_t;
using f32x4 = __attribute__((ext_vector_type(4))) float;

constexpr int SCAN_CHUNK = 1024;
constexpr int NBLK = (N_NODES + SCAN_CHUNK - 1) / SCAN_CHUNK; // 98

#define GLOAD_LDS16(gp, lp)                                                    \
    __builtin_amdgcn_global_load_lds(                                         \
        (const __attribute__((address_space(1))) void*)(gp),                  \
        (__attribute__((address_space(3))) void*)(lp), 16, 0, 0)

template <int N>
__device__ __forceinline__ void vmwait() {
    asm volatile("s_waitcnt vmcnt(%0)" :: "n"(N) : "memory");
}

// ---------------- CSR build ----------------
__global__ void k_count(const int* __restrict__ dst, int* __restrict__ deg) {
    int e = blockIdx.x * 256 + threadIdx.x;
    if (e < N_EDGES) atomicAdd(&deg[dst[e]], 1);
}

__global__ void k_blocksum(const int* __restrict__ deg, int* __restrict__ bsum) {
    __shared__ int sm[4];
    int b = blockIdx.x, t = threadIdx.x;
    int base = b * SCAN_CHUNK;
    int s = 0;
    for (int i = 0; i < 4; ++i) {
        int idx = base + t + i * 256;
        if (idx < N_NODES) s += deg[idx];
    }
    for (int off = 32; off; off >>= 1) s += __shfl_down(s, off);
    if ((t & 63) == 0) sm[t >> 6] = s;
    __syncthreads();
    if (t == 0) bsum[b] = sm[0] + sm[1] + sm[2] + sm[3];
}

__global__ void k_scan_bsum(const int* __restrict__ bsum, int* __restrict__ bscan) {
    if (threadIdx.x == 0) {
        int r = 0;
        for (int i = 0; i < NBLK; ++i) { bscan[i] = r; r += bsum[i]; }
    }
}

__global__ void k_scan_final(const int* __restrict__ deg, const int* __restrict__ bscan,
                             int* __restrict__ offsets, int* __restrict__ cursor) {
    __shared__ int sm[256];
    int b = blockIdx.x, t = threadIdx.x;
    int base = b * SCAN_CHUNK + t * 4;
    int c[4];
    for (int e = 0; e < 4; ++e) {
        int idx = base + e;
        c[e] = (idx < N_NODES) ? deg[idx] : 0;
    }
    int s = c[0] + c[1] + c[2] + c[3];
    sm[t] = s;
    __syncthreads();
    for (int off = 1; off < 256; off <<= 1) {
        int v = (t >= off) ? sm[t - off] : 0;
        __syncthreads();
        sm[t] += v;
        __syncthreads();
    }
    int run = sm[t] - s + bscan[b];
    for (int e = 0; e < 4; ++e) {
        int idx = base + e;
        if (idx < N_NODES) { offsets[idx] = run; cursor[idx] = run; }
        run += c[e];
    }
}

__global__ void k_fill(const int* __restrict__ src, const int* __restrict__ dst,
                       int* __restrict__ cursor, int* __restrict__ csr) {
    int e = blockIdx.x * 256 + threadIdx.x;
    if (e < N_EDGES) {
        int d = dst[e];
        int pos = atomicAdd(&cursor[d], 1);
        csr[pos] = src[e];
    }
}

// ---------------- fp32 -> fp16 convert ----------------
__global__ void k_tohalf(const float* __restrict__ in, half_t* __restrict__ out, int n8) {
    int i = blockIdx.x * 256 + threadIdx.x;
    if (i < n8) {
        float4 a = *reinterpret_cast<const float4*>(in + (size_t)i * 8);
        float4 b = *reinterpret_cast<const float4*>(in + (size_t)i * 8 + 4);
        f16x8 h;
        h[0] = (half_t)a.x; h[1] = (half_t)a.y; h[2] = (half_t)a.z; h[3] = (half_t)a.w;
        h[4] = (half_t)b.x; h[5] = (half_t)b.y; h[6] = (half_t)b.z; h[7] = (half_t)b.w;
        *reinterpret_cast<f16x8*>(out + (size_t)i * 8) = h;
    }
}

// ---------------- mean aggregation -> fp16 -------------------------------
__global__ __launch_bounds__(256) void k_aggregate_h(
    const half_t* __restrict__ xh, const int* __restrict__ offsets,
    const int* __restrict__ deg, const int* __restrict__ csr,
    half_t* __restrict__ aggH) {
    int wave = threadIdx.x >> 6;
    int lane = threadIdx.x & 63;
    int node = blockIdx.x * 4 + wave;
    int off = offsets[node];
    int dg = deg[node];
    const size_t lo4 = (size_t)lane * 4;
    float4 a0 = {0.f, 0.f, 0.f, 0.f}, a1 = a0, a2 = a0, a3 = a0;
    int j = 0;
    for (; j + 4 <= dg; j += 4) {
        int s0 = csr[off + j + 0];
        int s1 = csr[off + j + 1];
        int s2 = csr[off + j + 2];
        int s3 = csr[off + j + 3];
        f16x4 v0 = *reinterpret_cast<const f16x4*>(xh + (size_t)s0 * HID + lo4);
        f16x4 v1 = *reinterpret_cast<const f16x4*>(xh + (size_t)s1 * HID + lo4);
        f16x4 v2 = *reinterpret_cast<const f16x4*>(xh + (size_t)s2 * HID + lo4);
        f16x4 v3 = *reinterpret_cast<const f16x4*>(xh + (size_t)s3 * HID + lo4);
        a0.x += (float)v0[0]; a0.y += (float)v0[1]; a0.z += (float)v0[2]; a0.w += (float)v0[3];
        a1.x += (float)v1[0]; a1.y += (float)v1[1]; a1.z += (float)v1[2]; a1.w += (float)v1[3];
        a2.x += (float)v2[0]; a2.y += (float)v2[1]; a2.z += (float)v2[2]; a2.w += (float)v2[3];
        a3.x += (float)v3[0]; a3.y += (float)v3[1]; a3.z += (float)v3[2]; a3.w += (float)v3[3];
    }
    for (; j < dg; ++j) {
        int s = csr[off + j];
        f16x4 v = *reinterpret_cast<const f16x4*>(xh + (size_t)s * HID + lo4);
        a0.x += (float)v[0]; a0.y += (float)v[1]; a0.z += (float)v[2]; a0.w += (float)v[3];
    }
    float av[4];
    av[0] = (a0.x + a1.x) + (a2.x + a3.x);
    av[1] = (a0.y + a1.y) + (a2.y + a3.y);
    av[2] = (a0.z + a1.z) + (a2.z + a3.z);
    av[3] = (a0.w + a1.w) + (a2.w + a3.w);
    float inv = 1.0f / (float)(dg > 0 ? dg : 1);
    f16x4 hi;
#pragma unroll
    for (int c = 0; c < 4; ++c) hi[c] = (half_t)(av[c] * inv);
    *reinterpret_cast<f16x4*>(aggH + (size_t)node * HID + lo4) = hi;
}

// ---------------- weight transpose to fp16: [col][k] ----------------------
__global__ void k_transw(const float* __restrict__ W, half_t* __restrict__ out, int ncols) {
    int col = blockIdx.x;
    int k = threadIdx.x;
    out[(size_t)col * 256 + k] = (half_t)W[(size_t)k * ncols + col];
}

// ---------------- pure-fp16 double-buffered MFMA GEMM ---------------------
// C[M][BN] = relu?(bias + A1@B1 [+ A2@B2]); K=256 per op; all fp16 operands,
// fp32 accum. B pre-transposed [col][k]. Tile 128 x BN, 8 waves (2m x 4n).
// Per 32-k step: barrier; STAGE(t+1 -> buf^1); vmcnt(counted, never 0
// mid-loop); barrier; MFMA(t, buf). LDS = 2*(BN/128*16KB/2 + 8KB).
template <int BN, bool HASA2, bool OUTH>
__global__ __launch_bounds__(512, 4) void k_gemm_f16(
    const half_t* __restrict__ A1, const half_t* __restrict__ B1,
    const half_t* __restrict__ A2, const half_t* __restrict__ B2,
    const float* __restrict__ bias, void* Cv, int M, int doRelu) {
    constexpr int NF = BN / 64;          // n-fragments per wave
    constexpr int NSTEPS = HASA2 ? 16 : 8;
    constexpr int BL = BN / 128;         // B gloads per thread per stage

    __shared__ f16x8 sA[2][512];         // [kg(4)][row(128)]
    __shared__ f16x8 sB[2][BN * 4];      // [kg(4)][col(BN)]

    const int tid = threadIdx.x;
    const int lane = tid & 63;
    const int m0 = blockIdx.x * 128;
    const int skg = tid >> 7;
    const int srow = tid & 127;
    const int grow = min(m0 + srow, M - 1);
    const int l16 = lane & 15, fkg = lane >> 4;
    const int wid = tid >> 6, wm = wid >> 2, wn = wid & 3;  // 2m x 4n
    const int aBase = fkg * 128 + wm * 64 + l16;
    const int bBase = fkg * BN + wn * (BN / 4) + l16;

    f32x4 acc[4][NF] = {};

    auto STAGE = [&](int s, int buf) {
        const int op = HASA2 ? (s >> 3) : 0;
        const int kk = (s & 7) * 32;
        const half_t* Bp = (HASA2 && op) ? B2 : B1;
#pragma unroll
        for (int b = 0; b < BL; ++b) {
            int c = tid + b * 512;
            int col = c & (BN - 1);
            int ckg = (BN == 256) ? (c >> 8) : (c >> 7);
            GLOAD_LDS16(Bp + (size_t)col * 256 + kk + ckg * 8, &sB[buf][c]);
        }
        const half_t* Ap = (HASA2 && op) ? A2 : A1;
        GLOAD_LDS16(Ap + (size_t)grow * 256 + kk + skg * 8, &sA[buf][tid]);
    };

    STAGE(0, 0);

#pragma unroll
    for (int t = 0; t < NSTEPS; ++t) {
        const int buf = t & 1;
        // barrier 1: all waves done computing t-1 (buf^1) -> safe to restage
        __builtin_amdgcn_s_barrier();
        __builtin_amdgcn_sched_barrier(0);
        if (t + 1 < NSTEPS) STAGE(t + 1, buf ^ 1);
        // wait for stage t; stage t+1's (BL+1) loads stay in flight
        if (t + 1 < NSTEPS) vmwait<BL + 1>();
        else vmwait<0>();
        // barrier 2: everyone's stage-t loads landed
        __builtin_amdgcn_s_barrier();
        __builtin_amdgcn_sched_barrier(0);

        f16x8 ah[4];
#pragma unroll
        for (int mf = 0; mf < 4; ++mf) ah[mf] = sA[buf][aBase + mf * 16];
        __builtin_amdgcn_s_setprio(1);
#pragma unroll
        for (int nf = 0; nf < NF; ++nf) {
            f16x8 bh = sB[buf][bBase + nf * 16];
#pragma unroll
            for (int mf = 0; mf < 4; ++mf)
                acc[mf][nf] = __builtin_amdgcn_mfma_f32_16x16x32_f16(ah[mf], bh, acc[mf][nf], 0, 0, 0);
        }
        __builtin_amdgcn_s_setprio(0);
    }

    // epilogue: row = m0+wm*64+mf*16+(lane>>4)*4+r, col = wn*(BN/4)+nf*16+l16
#pragma unroll
    for (int mf = 0; mf < 4; ++mf) {
        int row = m0 + wm * 64 + mf * 16 + (lane >> 4) * 4;
#pragma unroll
        for (int nf = 0; nf < NF; ++nf) {
            int col = wn * (BN / 4) + nf * 16 + l16;
            float bv = bias[col];
#pragma unroll
            for (int r = 0; r < 4; ++r) {
                int gr = row + r;
                if (gr < M) {
                    float v = acc[mf][nf][r] + bv;
                    if (doRelu) v = fmaxf(v, 0.f);
                    if (OUTH)
                        ((half_t*)Cv)[(size_t)gr * BN + col] = (half_t)v;
                    else
                        ((float*)Cv)[(size_t)gr * BN + col] = v;
                }
            }
        }
    }
}

// ---------------- head: out = h @ W2 + b2   (128 -> 4) ----------------
__global__ void k_head(const float* __restrict__ h, const float* __restrict__ W2,
                       const float* __restrict__ b2, float* __restrict__ out) {
    int wave = threadIdx.x >> 6, lane = threadIdx.x & 63;
    int node = blockIdx.x * 4 + wave;
    const float* hr = h + (size_t)node * 128;
    float p0 = 0.f, p1 = 0.f, p2 = 0.f, p3 = 0.f;
    for (int j = lane; j < 128; j += 64) {
        float hv = hr[j];
        p0 += hv * W2[j * 4 + 0];
        p1 += hv * W2[j * 4 + 1];
        p2 += hv * W2[j * 4 + 2];
        p3 += hv * W2[j * 4 + 3];
    }
    for (int off = 32; off; off >>= 1) {
        p0 += __shfl_down(p0, off);
        p1 += __shfl_down(p1, off);
        p2 += __shfl_down(p2, off);
        p3 += __shfl_down(p3, off);
    }
    if (lane == 0) {
        float4 o = {p0 + b2[0], p1 + b2[1], p2 + b2[2], p3 + b2[3]};
        *reinterpret_cast<float4*>(out + (size_t)node * 4) = o;
    }
}

extern "C" void kernel_launch(void* const* d_in, const int* in_sizes, int n_in,
                              void* d_out, int out_size, void* d_ws, size_t ws_size,
                              hipStream_t stream) {
    const float* x  = (const float*)d_in[0];
    const int*   ei = (const int*)d_in[1];
    const float* Wl = (const float*)d_in[2];
    const float* bl = (const float*)d_in[3];
    const float* Wr = (const float*)d_in[4];
    const float* W1 = (const float*)d_in[5];
    const float* b1 = (const float*)d_in[6];
    const float* W2 = (const float*)d_in[7];
    const float* b2 = (const float*)d_in[8];
    float* out = (float*)d_out;

    char* w = (char*)d_ws;
    size_t o = 0;
    auto alloc = [&](size_t bytes) -> void* {
        void* p = w + o;
        o += (bytes + 255) & ~(size_t)255;
        return p;
    };
    int* deg     = (int*)alloc((size_t)N_NODES * 4);
    int* cursor  = (int*)alloc((size_t)N_NODES * 4);
    int* offsets = (int*)alloc((size_t)N_NODES * 4);
    int* bsum    = (int*)alloc((size_t)NBLK * 4);
    int* bscan   = (int*)alloc((size_t)NBLK * 4);
    int* csr     = (int*)alloc((size_t)N_EDGES * 4);
    half_t* aggH = (half_t*)alloc((size_t)N_NODES * HID * 2);
    half_t* xa   = (half_t*)alloc((size_t)N_NODES * HID * 2);
    half_t* xb   = (half_t*)alloc((size_t)N_NODES * HID * 2);
    half_t* WlT[3]; half_t* WrT[3];
    for (int l = 0; l < 3; ++l) {
        WlT[l] = (half_t*)alloc((size_t)256 * 256 * 2);
        WrT[l] = (half_t*)alloc((size_t)256 * 256 * 2);
    }
    half_t* W1T = (half_t*)alloc((size_t)128 * 256 * 2);
    float* h = (float*)alloc((size_t)N_NODES * 128 * 4);

    const int* srcA = ei;
    const int* dstA = ei + N_EDGES;

    for (int l = 0; l < 3; ++l) {
        k_transw<<<256, 256, 0, stream>>>(Wl + (size_t)l * 65536, WlT[l], 256);
        k_transw<<<256, 256, 0, stream>>>(Wr + (size_t)l * 65536, WrT[l], 256);
    }
    k_transw<<<128, 256, 0, stream>>>(W1, W1T, 128);
    k_tohalf<<<(N_NODES * HID / 8 + 255) / 256, 256, 0, stream>>>(x, xa, N_NODES * HID / 8);

    hipMemsetAsync(deg, 0, (size_t)N_NODES * 4, stream);
    k_count<<<(N_EDGES + 255) / 256, 256, 0, stream>>>(dstA, deg);
    k_blocksum<<<NBLK, 256, 0, stream>>>(deg, bsum);
    k_scan_bsum<<<1, 64, 0, stream>>>(bsum, bscan);
    k_scan_final<<<NBLK, 256, 0, stream>>>(deg, bscan, offsets, cursor);
    k_fill<<<(N_EDGES + 255) / 256, 256, 0, stream>>>(srcA, dstA, cursor, csr);

    const int mtiles = (N_NODES + 127) / 128;  // 782
    half_t* cur = xa;
    half_t* nxt = xb;
    for (int l = 0; l < 3; ++l) {
        k_aggregate_h<<<N_NODES / 4, 256, 0, stream>>>(cur, offsets, deg, csr, aggH);
        // nxt(fp16) = relu(bl + agg@Wl + cur@Wr)
        k_gemm_f16<256, true, true><<<mtiles, 512, 0, stream>>>(
            aggH, WlT[l], cur, WrT[l], bl + (size_t)l * 256, nxt, N_NODES, 1);
        half_t* tmp = cur; cur = nxt; nxt = tmp;
    }
    // h(fp32) = relu(cur@W1 + b1)
    k_gemm_f16<128, false, false><<<mtiles, 512, 0, stream>>>(
        cur, W1T, nullptr, nullptr, b1, h, N_NODES, 1);
    k_head<<<N_NODES / 4, 256, 0, stream>>>(h, W2, b2, out);
}

// Round 10
// 833.104 us; speedup vs baseline: 1.6513x; 1.0516x over previous
//
#include <hip/hip_runtime.h>

#define N_NODES 100000
#define N_EDGES 1600000
#define HID 256

typedef _Float16 half_t;
using f16x8 = __attribute__((ext_vector_type(8))) half_t;
using f16x4 = __attribute__((ext_vector_type(4))) half_t;
using f32x4 = __attribute__((ext_vector_type(4))) float;

constexpr int SCAN_CHUNK = 1024;
constexpr int NBLK = (N_NODES + SCAN_CHUNK - 1) / SCAN_CHUNK; // 98
constexpr int FILL_EPB = 4096;
constexpr int FILL_CHUNKS = (N_EDGES + FILL_EPB - 1) / FILL_EPB; // 391

#define GLOAD_LDS16(gp, lp)                                                    \
    __builtin_amdgcn_global_load_lds(                                         \
        (const __attribute__((address_space(1))) void*)(gp),                  \
        (__attribute__((address_space(3))) void*)(lp), 16, 0, 0)

template <int N>
__device__ __forceinline__ void vmwait() {
    asm volatile("s_waitcnt vmcnt(%0)" :: "n"(N) : "memory");
}

// ---------------- CSR build ----------------
__global__ void k_count(const int* __restrict__ dst, int* __restrict__ deg) {
    int e = blockIdx.x * 256 + threadIdx.x;
    if (e < N_EDGES) atomicAdd(&deg[dst[e]], 1);
}

__global__ void k_blocksum(const int* __restrict__ deg, int* __restrict__ bsum) {
    __shared__ int sm[4];
    int b = blockIdx.x, t = threadIdx.x;
    int base = b * SCAN_CHUNK;
    int s = 0;
    for (int i = 0; i < 4; ++i) {
        int idx = base + t + i * 256;
        if (idx < N_NODES) s += deg[idx];
    }
    for (int off = 32; off; off >>= 1) s += __shfl_down(s, off);
    if ((t & 63) == 0) sm[t >> 6] = s;
    __syncthreads();
    if (t == 0) bsum[b] = sm[0] + sm[1] + sm[2] + sm[3];
}

__global__ void k_scan_bsum(const int* __restrict__ bsum, int* __restrict__ bscan) {
    if (threadIdx.x == 0) {
        int r = 0;
        for (int i = 0; i < NBLK; ++i) { bscan[i] = r; r += bsum[i]; }
    }
}

__global__ void k_scan_final(const int* __restrict__ deg, const int* __restrict__ bscan,
                             int* __restrict__ offsets, int* __restrict__ cursor) {
    __shared__ int sm[256];
    int b = blockIdx.x, t = threadIdx.x;
    int base = b * SCAN_CHUNK + t * 4;
    int c[4];
    for (int e = 0; e < 4; ++e) {
        int idx = base + e;
        c[e] = (idx < N_NODES) ? deg[idx] : 0;
    }
    int s = c[0] + c[1] + c[2] + c[3];
    sm[t] = s;
    __syncthreads();
    for (int off = 1; off < 256; off <<= 1) {
        int v = (t >= off) ? sm[t - off] : 0;
        __syncthreads();
        sm[t] += v;
        __syncthreads();
    }
    int run = sm[t] - s + bscan[b];
    for (int e = 0; e < 4; ++e) {
        int idx = base + e;
        if (idx < N_NODES) { offsets[idx] = run; cursor[idx] = run; }
        run += c[e];
    }
}

// XCD-partitioned fill: block b -> edge chunk (b>>3), dst-range (b&7).
// With round-robin blockIdx->XCD mapping, all writes to one csr slice come
// from one XCD's L2 -> full-line writebacks (fixes 105 MB partial-line HBM
// write traffic). Correct regardless of actual XCD mapping.
__global__ __launch_bounds__(256) void k_fill_xcd(
    const int* __restrict__ src, const int* __restrict__ dst,
    int* __restrict__ cursor, int* __restrict__ csr) {
    const int part = blockIdx.x & 7;
    const int chunk = blockIdx.x >> 3;
    const int lo = part * (N_NODES / 8);
    const int hi = lo + (N_NODES / 8);
    const int ebeg = chunk * FILL_EPB + threadIdx.x;
    const int eend = min((chunk + 1) * FILL_EPB, N_EDGES);
    for (int e = ebeg; e < eend; e += 256) {
        int d = dst[e];
        if (d >= lo && d < hi) {
            int pos = atomicAdd(&cursor[d], 1);
            csr[pos] = src[e];
        }
    }
}

// ---------------- fp32 -> fp16 convert ----------------
__global__ void k_tohalf(const float* __restrict__ in, half_t* __restrict__ out, int n8) {
    int i = blockIdx.x * 256 + threadIdx.x;
    if (i < n8) {
        float4 a = *reinterpret_cast<const float4*>(in + (size_t)i * 8);
        float4 b = *reinterpret_cast<const float4*>(in + (size_t)i * 8 + 4);
        f16x8 h;
        h[0] = (half_t)a.x; h[1] = (half_t)a.y; h[2] = (half_t)a.z; h[3] = (half_t)a.w;
        h[4] = (half_t)b.x; h[5] = (half_t)b.y; h[6] = (half_t)b.z; h[7] = (half_t)b.w;
        *reinterpret_cast<f16x8*>(out + (size_t)i * 8) = h;
    }
}

// ---------------- mean aggregation -> fp16 -------------------------------
__global__ __launch_bounds__(256) void k_aggregate_h(
    const half_t* __restrict__ xh, const int* __restrict__ offsets,
    const int* __restrict__ deg, const int* __restrict__ csr,
    half_t* __restrict__ aggH) {
    int wave = threadIdx.x >> 6;
    int lane = threadIdx.x & 63;
    int node = blockIdx.x * 4 + wave;
    int off = offsets[node];
    int dg = deg[node];
    const size_t lo4 = (size_t)lane * 4;
    float4 a0 = {0.f, 0.f, 0.f, 0.f}, a1 = a0, a2 = a0, a3 = a0;
    int j = 0;
    for (; j + 4 <= dg; j += 4) {
        int s0 = csr[off + j + 0];
        int s1 = csr[off + j + 1];
        int s2 = csr[off + j + 2];
        int s3 = csr[off + j + 3];
        f16x4 v0 = *reinterpret_cast<const f16x4*>(xh + (size_t)s0 * HID + lo4);
        f16x4 v1 = *reinterpret_cast<const f16x4*>(xh + (size_t)s1 * HID + lo4);
        f16x4 v2 = *reinterpret_cast<const f16x4*>(xh + (size_t)s2 * HID + lo4);
        f16x4 v3 = *reinterpret_cast<const f16x4*>(xh + (size_t)s3 * HID + lo4);
        a0.x += (float)v0[0]; a0.y += (float)v0[1]; a0.z += (float)v0[2]; a0.w += (float)v0[3];
        a1.x += (float)v1[0]; a1.y += (float)v1[1]; a1.z += (float)v1[2]; a1.w += (float)v1[3];
        a2.x += (float)v2[0]; a2.y += (float)v2[1]; a2.z += (float)v2[2]; a2.w += (float)v2[3];
        a3.x += (float)v3[0]; a3.y += (float)v3[1]; a3.z += (float)v3[2]; a3.w += (float)v3[3];
    }
    for (; j < dg; ++j) {
        int s = csr[off + j];
        f16x4 v = *reinterpret_cast<const f16x4*>(xh + (size_t)s * HID + lo4);
        a0.x += (float)v[0]; a0.y += (float)v[1]; a0.z += (float)v[2]; a0.w += (float)v[3];
    }
    float av[4];
    av[0] = (a0.x + a1.x) + (a2.x + a3.x);
    av[1] = (a0.y + a1.y) + (a2.y + a3.y);
    av[2] = (a0.z + a1.z) + (a2.z + a3.z);
    av[3] = (a0.w + a1.w) + (a2.w + a3.w);
    float inv = 1.0f / (float)(dg > 0 ? dg : 1);
    f16x4 hi;
#pragma unroll
    for (int c = 0; c < 4; ++c) hi[c] = (half_t)(av[c] * inv);
    *reinterpret_cast<f16x4*>(aggH + (size_t)node * HID + lo4) = hi;
}

// ---------------- weight transpose to fp16: [col][k] ----------------------
__global__ void k_transw(const float* __restrict__ W, half_t* __restrict__ out, int ncols) {
    int col = blockIdx.x;
    int k = threadIdx.x;
    out[(size_t)col * 256 + k] = (half_t)W[(size_t)k * ncols + col];
}

// ---------------- pure-fp16 double-buffered MFMA GEMM ---------------------
// C[M][BN] = relu?(bias + A1@B1 [+ A2@B2]); K=256 per op; all fp16 operands,
// fp32 accum. B pre-transposed [col][k]. Tile 128 x BN, 8 waves (2m x 4n).
// Per 32-k step: barrier; STAGE(t+1 -> buf^1); vmcnt(counted, never 0
// mid-loop); barrier; MFMA(t, buf).
template <int BN, bool HASA2, bool OUTH>
__global__ __launch_bounds__(512, 4) void k_gemm_f16(
    const half_t* __restrict__ A1, const half_t* __restrict__ B1,
    const half_t* __restrict__ A2, const half_t* __restrict__ B2,
    const float* __restrict__ bias, void* Cv, int M, int doRelu) {
    constexpr int NF = BN / 64;          // n-fragments per wave
    constexpr int NSTEPS = HASA2 ? 16 : 8;
    constexpr int BL = BN / 128;         // B gloads per thread per stage

    __shared__ f16x8 sA[2][512];         // [kg(4)][row(128)]
    __shared__ f16x8 sB[2][BN * 4];      // [kg(4)][col(BN)]

    const int tid = threadIdx.x;
    const int lane = tid & 63;
    const int m0 = blockIdx.x * 128;
    const int skg = tid >> 7;
    const int srow = tid & 127;
    const int grow = min(m0 + srow, M - 1);
    const int l16 = lane & 15, fkg = lane >> 4;
    const int wid = tid >> 6, wm = wid >> 2, wn = wid & 3;  // 2m x 4n
    const int aBase = fkg * 128 + wm * 64 + l16;
    const int bBase = fkg * BN + wn * (BN / 4) + l16;

    f32x4 acc[4][NF] = {};

    auto STAGE = [&](int s, int buf) {
        const int op = HASA2 ? (s >> 3) : 0;
        const int kk = (s & 7) * 32;
        const half_t* Bp = (HASA2 && op) ? B2 : B1;
#pragma unroll
        for (int b = 0; b < BL; ++b) {
            int c = tid + b * 512;
            int col = c & (BN - 1);
            int ckg = (BN == 256) ? (c >> 8) : (c >> 7);
            GLOAD_LDS16(Bp + (size_t)col * 256 + kk + ckg * 8, &sB[buf][c]);
        }
        const half_t* Ap = (HASA2 && op) ? A2 : A1;
        GLOAD_LDS16(Ap + (size_t)grow * 256 + kk + skg * 8, &sA[buf][tid]);
    };

    STAGE(0, 0);

#pragma unroll
    for (int t = 0; t < NSTEPS; ++t) {
        const int buf = t & 1;
        // barrier 1: all waves done computing t-1 (buf^1) -> safe to restage
        __builtin_amdgcn_s_barrier();
        __builtin_amdgcn_sched_barrier(0);
        if (t + 1 < NSTEPS) STAGE(t + 1, buf ^ 1);
        // wait for stage t; stage t+1's (BL+1) loads stay in flight
        if (t + 1 < NSTEPS) vmwait<BL + 1>();
        else vmwait<0>();
        // barrier 2: everyone's stage-t loads landed
        __builtin_amdgcn_s_barrier();
        __builtin_amdgcn_sched_barrier(0);

        f16x8 ah[4];
#pragma unroll
        for (int mf = 0; mf < 4; ++mf) ah[mf] = sA[buf][aBase + mf * 16];
        __builtin_amdgcn_s_setprio(1);
#pragma unroll
        for (int nf = 0; nf < NF; ++nf) {
            f16x8 bh = sB[buf][bBase + nf * 16];
#pragma unroll
            for (int mf = 0; mf < 4; ++mf)
                acc[mf][nf] = __builtin_amdgcn_mfma_f32_16x16x32_f16(ah[mf], bh, acc[mf][nf], 0, 0, 0);
        }
        __builtin_amdgcn_s_setprio(0);
    }

    // epilogue: row = m0+wm*64+mf*16+(lane>>4)*4+r, col = wn*(BN/4)+nf*16+l16
#pragma unroll
    for (int mf = 0; mf < 4; ++mf) {
        int row = m0 + wm * 64 + mf * 16 + (lane >> 4) * 4;
#pragma unroll
        for (int nf = 0; nf < NF; ++nf) {
            int col = wn * (BN / 4) + nf * 16 + l16;
            float bv = bias[col];
#pragma unroll
            for (int r = 0; r < 4; ++r) {
                int gr = row + r;
                if (gr < M) {
                    float v = acc[mf][nf][r] + bv;
                    if (doRelu) v = fmaxf(v, 0.f);
                    if (OUTH)
                        ((half_t*)Cv)[(size_t)gr * BN + col] = (half_t)v;
                    else
                        ((float*)Cv)[(size_t)gr * BN + col] = v;
                }
            }
        }
    }
}

// ---------------- head: out = h @ W2 + b2   (128 -> 4) ----------------
__global__ void k_head(const float* __restrict__ h, const float* __restrict__ W2,
                       const float* __restrict__ b2, float* __restrict__ out) {
    int wave = threadIdx.x >> 6, lane = threadIdx.x & 63;
    int node = blockIdx.x * 4 + wave;
    const float* hr = h + (size_t)node * 128;
    float p0 = 0.f, p1 = 0.f, p2 = 0.f, p3 = 0.f;
    for (int j = lane; j < 128; j += 64) {
        float hv = hr[j];
        p0 += hv * W2[j * 4 + 0];
        p1 += hv * W2[j * 4 + 1];
        p2 += hv * W2[j * 4 + 2];
        p3 += hv * W2[j * 4 + 3];
    }
    for (int off = 32; off; off >>= 1) {
        p0 += __shfl_down(p0, off);
        p1 += __shfl_down(p1, off);
        p2 += __shfl_down(p2, off);
        p3 += __shfl_down(p3, off);
    }
    if (lane == 0) {
        float4 o = {p0 + b2[0], p1 + b2[1], p2 + b2[2], p3 + b2[3]};
        *reinterpret_cast<float4*>(out + (size_t)node * 4) = o;
    }
}

extern "C" void kernel_launch(void* const* d_in, const int* in_sizes, int n_in,
                              void* d_out, int out_size, void* d_ws, size_t ws_size,
                              hipStream_t stream) {
    const float* x  = (const float*)d_in[0];
    const int*   ei = (const int*)d_in[1];
    const float* Wl = (const float*)d_in[2];
    const float* bl = (const float*)d_in[3];
    const float* Wr = (const float*)d_in[4];
    const float* W1 = (const float*)d_in[5];
    const float* b1 = (const float*)d_in[6];
    const float* W2 = (const float*)d_in[7];
    const float* b2 = (const float*)d_in[8];
    float* out = (float*)d_out;

    char* w = (char*)d_ws;
    size_t o = 0;
    auto alloc = [&](size_t bytes) -> void* {
        void* p = w + o;
        o += (bytes + 255) & ~(size_t)255;
        return p;
    };
    int* deg     = (int*)alloc((size_t)N_NODES * 4);
    int* cursor  = (int*)alloc((size_t)N_NODES * 4);
    int* offsets = (int*)alloc((size_t)N_NODES * 4);
    int* bsum    = (int*)alloc((size_t)NBLK * 4);
    int* bscan   = (int*)alloc((size_t)NBLK * 4);
    int* csr     = (int*)alloc((size_t)N_EDGES * 4);
    half_t* aggH = (half_t*)alloc((size_t)N_NODES * HID * 2);
    half_t* xa   = (half_t*)alloc((size_t)N_NODES * HID * 2);
    half_t* xb   = (half_t*)alloc((size_t)N_NODES * HID * 2);
    half_t* WlT[3]; half_t* WrT[3];
    for (int l = 0; l < 3; ++l) {
        WlT[l] = (half_t*)alloc((size_t)256 * 256 * 2);
        WrT[l] = (half_t*)alloc((size_t)256 * 256 * 2);
    }
    half_t* W1T = (half_t*)alloc((size_t)128 * 256 * 2);
    float* h = (float*)alloc((size_t)N_NODES * 128 * 4);

    const int* srcA = ei;
    const int* dstA = ei + N_EDGES;

    for (int l = 0; l < 3; ++l) {
        k_transw<<<256, 256, 0, stream>>>(Wl + (size_t)l * 65536, WlT[l], 256);
        k_transw<<<256, 256, 0, stream>>>(Wr + (size_t)l * 65536, WrT[l], 256);
    }
    k_transw<<<128, 256, 0, stream>>>(W1, W1T, 128);
    k_tohalf<<<(N_NODES * HID / 8 + 255) / 256, 256, 0, stream>>>(x, xa, N_NODES * HID / 8);

    hipMemsetAsync(deg, 0, (size_t)N_NODES * 4, stream);
    k_count<<<(N_EDGES + 255) / 256, 256, 0, stream>>>(dstA, deg);
    k_blocksum<<<NBLK, 256, 0, stream>>>(deg, bsum);
    k_scan_bsum<<<1, 64, 0, stream>>>(bsum, bscan);
    k_scan_final<<<NBLK, 256, 0, stream>>>(deg, bscan, offsets, cursor);
    k_fill_xcd<<<FILL_CHUNKS * 8, 256, 0, stream>>>(srcA, dstA, cursor, csr);

    const int mtiles = (N_NODES + 127) / 128;  // 782
    half_t* cur = xa;
    half_t* nxt = xb;
    for (int l = 0; l < 3; ++l) {
        k_aggregate_h<<<N_NODES / 4, 256, 0, stream>>>(cur, offsets, deg, csr, aggH);
        // nxt(fp16) = relu(bl + agg@Wl + cur@Wr)
        k_gemm_f16<256, true, true><<<mtiles, 512, 0, stream>>>(
            aggH, WlT[l], cur, WrT[l], bl + (size_t)l * 256, nxt, N_NODES, 1);
        half_t* tmp = cur; cur = nxt; nxt = tmp;
    }
    // h(fp32) = relu(cur@W1 + b1)
    k_gemm_f16<128, false, false><<<mtiles, 512, 0, stream>>>(
        cur, W1T, nullptr, nullptr, b1, h, N_NODES, 1);
    k_head<<<N_NODES / 4, 256, 0, stream>>>(h, W2, b2, out);
}

// Round 11
// 804.748 us; speedup vs baseline: 1.7095x; 1.0352x over previous
//
#include <hip/hip_runtime.h>

#define N_NODES 100000
#define N_EDGES 1600000
#define HID 256

typedef _Float16 half_t;
using f16x8 = __attribute__((ext_vector_type(8))) half_t;
using f16x4 = __attribute__((ext_vector_type(4))) half_t;
using f32x4 = __attribute__((ext_vector_type(4))) float;

constexpr int SCAN_CHUNK = 1024;
constexpr int NBLK = (N_NODES + SCAN_CHUNK - 1) / SCAN_CHUNK; // 98
constexpr int FILL_EPB = 4096;
constexpr int FILL_CHUNKS = (N_EDGES + FILL_EPB - 1) / FILL_EPB; // 391

#define GLOAD_LDS16(gp, lp)                                                    \
    __builtin_amdgcn_global_load_lds(                                         \
        (const __attribute__((address_space(1))) void*)(gp),                  \
        (__attribute__((address_space(3))) void*)(lp), 16, 0, 0)

template <int N>
__device__ __forceinline__ void vmwait() {
    asm volatile("s_waitcnt vmcnt(%0)" :: "n"(N) : "memory");
}

// ---------------- CSR build ----------------
__global__ void k_count(const int* __restrict__ dst, int* __restrict__ deg) {
    int e = blockIdx.x * 256 + threadIdx.x;
    if (e < N_EDGES) atomicAdd(&deg[dst[e]], 1);
}

__global__ void k_blocksum(const int* __restrict__ deg, int* __restrict__ bsum) {
    __shared__ int sm[4];
    int b = blockIdx.x, t = threadIdx.x;
    int base = b * SCAN_CHUNK;
    int s = 0;
    for (int i = 0; i < 4; ++i) {
        int idx = base + t + i * 256;
        if (idx < N_NODES) s += deg[idx];
    }
    for (int off = 32; off; off >>= 1) s += __shfl_down(s, off);
    if ((t & 63) == 0) sm[t >> 6] = s;
    __syncthreads();
    if (t == 0) bsum[b] = sm[0] + sm[1] + sm[2] + sm[3];
}

__global__ void k_scan_bsum(const int* __restrict__ bsum, int* __restrict__ bscan) {
    if (threadIdx.x == 0) {
        int r = 0;
        for (int i = 0; i < NBLK; ++i) { bscan[i] = r; r += bsum[i]; }
    }
}

__global__ void k_scan_final(const int* __restrict__ deg, const int* __restrict__ bscan,
                             int* __restrict__ offsets, int* __restrict__ cursor) {
    __shared__ int sm[256];
    int b = blockIdx.x, t = threadIdx.x;
    int base = b * SCAN_CHUNK + t * 4;
    int c[4];
    for (int e = 0; e < 4; ++e) {
        int idx = base + e;
        c[e] = (idx < N_NODES) ? deg[idx] : 0;
    }
    int s = c[0] + c[1] + c[2] + c[3];
    sm[t] = s;
    __syncthreads();
    for (int off = 1; off < 256; off <<= 1) {
        int v = (t >= off) ? sm[t - off] : 0;
        __syncthreads();
        sm[t] += v;
        __syncthreads();
    }
    int run = sm[t] - s + bscan[b];
    for (int e = 0; e < 4; ++e) {
        int idx = base + e;
        if (idx < N_NODES) { offsets[idx] = run; cursor[idx] = run; }
        run += c[e];
    }
}

// XCD-partitioned fill (R10 win): full-line writebacks per XCD-local slice.
__global__ __launch_bounds__(256) void k_fill_xcd(
    const int* __restrict__ src, const int* __restrict__ dst,
    int* __restrict__ cursor, int* __restrict__ csr) {
    const int part = blockIdx.x & 7;
    const int chunk = blockIdx.x >> 3;
    const int lo = part * (N_NODES / 8);
    const int hi = lo + (N_NODES / 8);
    const int ebeg = chunk * FILL_EPB + threadIdx.x;
    const int eend = min((chunk + 1) * FILL_EPB, N_EDGES);
    for (int e = ebeg; e < eend; e += 256) {
        int d = dst[e];
        if (d >= lo && d < hi) {
            int pos = atomicAdd(&cursor[d], 1);
            csr[pos] = src[e];
        }
    }
}

// ---------------- fp32 -> fp16 convert ----------------
__global__ void k_tohalf(const float* __restrict__ in, half_t* __restrict__ out, int n8) {
    int i = blockIdx.x * 256 + threadIdx.x;
    if (i < n8) {
        float4 a = *reinterpret_cast<const float4*>(in + (size_t)i * 8);
        float4 b = *reinterpret_cast<const float4*>(in + (size_t)i * 8 + 4);
        f16x8 h;
        h[0] = (half_t)a.x; h[1] = (half_t)a.y; h[2] = (half_t)a.z; h[3] = (half_t)a.w;
        h[4] = (half_t)b.x; h[5] = (half_t)b.y; h[6] = (half_t)b.z; h[7] = (half_t)b.w;
        *reinterpret_cast<f16x8*>(out + (size_t)i * 8) = h;
    }
}

// ---------------- mean aggregation -> fp16 -------------------------------
__global__ __launch_bounds__(256) void k_aggregate_h(
    const half_t* __restrict__ xh, const int* __restrict__ offsets,
    const int* __restrict__ deg, const int* __restrict__ csr,
    half_t* __restrict__ aggH) {
    int wave = threadIdx.x >> 6;
    int lane = threadIdx.x & 63;
    int node = blockIdx.x * 4 + wave;
    int off = offsets[node];
    int dg = deg[node];
    const size_t lo4 = (size_t)lane * 4;
    float4 a0 = {0.f, 0.f, 0.f, 0.f}, a1 = a0, a2 = a0, a3 = a0;
    int j = 0;
    for (; j + 4 <= dg; j += 4) {
        int s0 = csr[off + j + 0];
        int s1 = csr[off + j + 1];
        int s2 = csr[off + j + 2];
        int s3 = csr[off + j + 3];
        f16x4 v0 = *reinterpret_cast<const f16x4*>(xh + (size_t)s0 * HID + lo4);
        f16x4 v1 = *reinterpret_cast<const f16x4*>(xh + (size_t)s1 * HID + lo4);
        f16x4 v2 = *reinterpret_cast<const f16x4*>(xh + (size_t)s2 * HID + lo4);
        f16x4 v3 = *reinterpret_cast<const f16x4*>(xh + (size_t)s3 * HID + lo4);
        a0.x += (float)v0[0]; a0.y += (float)v0[1]; a0.z += (float)v0[2]; a0.w += (float)v0[3];
        a1.x += (float)v1[0]; a1.y += (float)v1[1]; a1.z += (float)v1[2]; a1.w += (float)v1[3];
        a2.x += (float)v2[0]; a2.y += (float)v2[1]; a2.z += (float)v2[2]; a2.w += (float)v2[3];
        a3.x += (float)v3[0]; a3.y += (float)v3[1]; a3.z += (float)v3[2]; a3.w += (float)v3[3];
    }
    for (; j < dg; ++j) {
        int s = csr[off + j];
        f16x4 v = *reinterpret_cast<const f16x4*>(xh + (size_t)s * HID + lo4);
        a0.x += (float)v[0]; a0.y += (float)v[1]; a0.z += (float)v[2]; a0.w += (float)v[3];
    }
    float av[4];
    av[0] = (a0.x + a1.x) + (a2.x + a3.x);
    av[1] = (a0.y + a1.y) + (a2.y + a3.y);
    av[2] = (a0.z + a1.z) + (a2.z + a3.z);
    av[3] = (a0.w + a1.w) + (a2.w + a3.w);
    float inv = 1.0f / (float)(dg > 0 ? dg : 1);
    f16x4 hi;
#pragma unroll
    for (int c = 0; c < 4; ++c) hi[c] = (half_t)(av[c] * inv);
    *reinterpret_cast<f16x4*>(aggH + (size_t)node * HID + lo4) = hi;
}

// ---------------- weight transpose to fp16: [col][k] ----------------------
__global__ void k_transw(const float* __restrict__ W, half_t* __restrict__ out, int ncols) {
    int col = blockIdx.x;
    int k = threadIdx.x;
    out[(size_t)col * 256 + k] = (half_t)W[(size_t)k * ncols + col];
}

// ---------------- fp16 MFMA GEMM: 3-buffer, prefetch depth 2 ---------------
// C[M][BN] = relu?(bias + A1@B1 [+ A2@B2]); K=256/op; fp16 operands, fp32 acc.
// Per step t: barrier1 (buf (t+2)%3 free); STAGE(t+2); vmcnt(2*LPS) [stages
// t+1,t+2 stay in flight -> stage t has ~2 steps to land]; barrier2; MFMA(t).
// LDS = 3*(8KB A + BN/256*16KB B) = 72KB @BN=256 -> 2 blocks/CU retained.
template <int BN, bool HASA2, bool OUTH>
__global__ __launch_bounds__(512, 4) void k_gemm_f16(
    const half_t* __restrict__ A1, const half_t* __restrict__ B1,
    const half_t* __restrict__ A2, const half_t* __restrict__ B2,
    const float* __restrict__ bias, void* Cv, int M, int doRelu) {
    constexpr int NF = BN / 64;
    constexpr int NSTEPS = HASA2 ? 16 : 8;
    constexpr int BL = BN / 128;
    constexpr int LPS = BL + 1;

    __shared__ f16x8 sA[3][512];         // [kg(4)][row(128)]
    __shared__ f16x8 sB[3][BN * 4];      // [kg(4)][col(BN)]

    const int tid = threadIdx.x;
    const int lane = tid & 63;
    const int m0 = blockIdx.x * 128;
    const int skg = tid >> 7;
    const int srow = tid & 127;
    const int grow = min(m0 + srow, M - 1);
    const int l16 = lane & 15, fkg = lane >> 4;
    const int wid = tid >> 6, wm = wid >> 2, wn = wid & 3;  // 2m x 4n
    const int aBase = fkg * 128 + wm * 64 + l16;
    const int bBase = fkg * BN + wn * (BN / 4) + l16;

    f32x4 acc[4][NF] = {};

    auto STAGE = [&](int s, int buf) {
        const int op = HASA2 ? (s >> 3) : 0;
        const int kk = (s & 7) * 32;
        const half_t* Bp = (HASA2 && op) ? B2 : B1;
#pragma unroll
        for (int b = 0; b < BL; ++b) {
            int c = tid + b * 512;
            int col = c & (BN - 1);
            int ckg = (BN == 256) ? (c >> 8) : (c >> 7);
            GLOAD_LDS16(Bp + (size_t)col * 256 + kk + ckg * 8, &sB[buf][c]);
        }
        const half_t* Ap = (HASA2 && op) ? A2 : A1;
        GLOAD_LDS16(Ap + (size_t)grow * 256 + kk + skg * 8, &sA[buf][tid]);
    };

    STAGE(0, 0);
    STAGE(1, 1);

#pragma unroll
    for (int t = 0; t < NSTEPS; ++t) {
        const int buf = t % 3;
        // barrier 1: all waves done computing t-1 -> buf (t+2)%3 reusable
        __builtin_amdgcn_s_barrier();
        __builtin_amdgcn_sched_barrier(0);
        if (t + 2 < NSTEPS) STAGE(t + 2, (t + 2) % 3);
        // wait for stage t only; stages t+1,t+2 stay in flight
        if (t + 2 < NSTEPS) vmwait<2 * LPS>();
        else if (t + 1 < NSTEPS) vmwait<LPS>();
        else vmwait<0>();
        // barrier 2: everyone's stage-t loads landed
        __builtin_amdgcn_s_barrier();
        __builtin_amdgcn_sched_barrier(0);

        f16x8 ah[4];
#pragma unroll
        for (int mf = 0; mf < 4; ++mf) ah[mf] = sA[buf][aBase + mf * 16];
        __builtin_amdgcn_s_setprio(1);
#pragma unroll
        for (int nf = 0; nf < NF; ++nf) {
            f16x8 bh = sB[buf][bBase + nf * 16];
#pragma unroll
            for (int mf = 0; mf < 4; ++mf)
                acc[mf][nf] = __builtin_amdgcn_mfma_f32_16x16x32_f16(ah[mf], bh, acc[mf][nf], 0, 0, 0);
        }
        __builtin_amdgcn_s_setprio(0);
    }

    // epilogue
#pragma unroll
    for (int mf = 0; mf < 4; ++mf) {
        int row = m0 + wm * 64 + mf * 16 + (lane >> 4) * 4;
#pragma unroll
        for (int nf = 0; nf < NF; ++nf) {
            int col = wn * (BN / 4) + nf * 16 + l16;
            float bv = bias[col];
#pragma unroll
            for (int r = 0; r < 4; ++r) {
                int gr = row + r;
                if (gr < M) {
                    float v = acc[mf][nf][r] + bv;
                    if (doRelu) v = fmaxf(v, 0.f);
                    if (OUTH)
                        ((half_t*)Cv)[(size_t)gr * BN + col] = (half_t)v;
                    else
                        ((float*)Cv)[(size_t)gr * BN + col] = v;
                }
            }
        }
    }
}

// ---------------- fused MLP + head: out = relu(x@W1+b1) @ W2 + b2 ---------
// K-loop identical to k_gemm_f16<128,false> (3-buf depth-2); h-tile (128x128
// fp16) never leaves LDS; then 4 threads/row reduce h@W2 and write out[.][4].
__global__ __launch_bounds__(512, 4) void k_mlp_head(
    const half_t* __restrict__ A1, const half_t* __restrict__ B1,
    const float* __restrict__ b1, const float* __restrict__ W2,
    const float* __restrict__ b2, float* __restrict__ out, int M) {
    constexpr int NSTEPS = 8;
    __shared__ f16x8 sAB[3 * 512 + 3 * 512];  // 48KB staging; hTile aliases [0,32KB)
    __shared__ float sW2[512];                // W2 [128][4]
    f16x8 (*sA)[512] = (f16x8(*)[512])sAB;
    f16x8 (*sB)[512] = (f16x8(*)[512])(sAB + 3 * 512);
    half_t* hTile = (half_t*)sAB;

    const int tid = threadIdx.x;
    const int lane = tid & 63;
    const int m0 = blockIdx.x * 128;
    const int skg = tid >> 7;
    const int srow = tid & 127;
    const int grow = min(m0 + srow, M - 1);
    const int l16 = lane & 15, fkg = lane >> 4;
    const int wid = tid >> 6, wm = wid >> 2, wn = wid & 3;
    const int aBase = fkg * 128 + wm * 64 + l16;
    const int bBase = fkg * 128 + wn * 32 + l16;

    // preload W2 to LDS (before any gload_lds so vmcnt accounting stays clean)
    sW2[tid & 511] = W2[tid & 511];
    asm volatile("s_waitcnt lgkmcnt(0)" ::: "memory");

    f32x4 acc[4][2] = {};

    auto STAGE = [&](int s, int buf) {
        const int kk = s * 32;
        int col = tid & 127;
        int ckg = tid >> 7;
        GLOAD_LDS16(B1 + (size_t)col * 256 + kk + ckg * 8, &sB[buf][tid]);
        GLOAD_LDS16(A1 + (size_t)grow * 256 + kk + skg * 8, &sA[buf][tid]);
    };

    STAGE(0, 0);
    STAGE(1, 1);

#pragma unroll
    for (int t = 0; t < NSTEPS; ++t) {
        const int buf = t % 3;
        __builtin_amdgcn_s_barrier();
        __builtin_amdgcn_sched_barrier(0);
        if (t + 2 < NSTEPS) STAGE(t + 2, (t + 2) % 3);
        if (t + 2 < NSTEPS) vmwait<4>();
        else if (t + 1 < NSTEPS) vmwait<2>();
        else vmwait<0>();
        __builtin_amdgcn_s_barrier();
        __builtin_amdgcn_sched_barrier(0);

        f16x8 ah[4];
#pragma unroll
        for (int mf = 0; mf < 4; ++mf) ah[mf] = sA[buf][aBase + mf * 16];
        __builtin_amdgcn_s_setprio(1);
#pragma unroll
        for (int nf = 0; nf < 2; ++nf) {
            f16x8 bh = sB[buf][bBase + nf * 16];
#pragma unroll
            for (int mf = 0; mf < 4; ++mf)
                acc[mf][nf] = __builtin_amdgcn_mfma_f32_16x16x32_f16(ah[mf], bh, acc[mf][nf], 0, 0, 0);
        }
        __builtin_amdgcn_s_setprio(0);
    }

    __syncthreads();  // staging done everywhere; smem reusable as hTile
    // write relu(h + b1) tile to LDS
#pragma unroll
    for (int mf = 0; mf < 4; ++mf) {
        int rowl = wm * 64 + mf * 16 + (lane >> 4) * 4;
#pragma unroll
        for (int nf = 0; nf < 2; ++nf) {
            int col = wn * 32 + nf * 16 + l16;
            float bv = b1[col];
#pragma unroll
            for (int r = 0; r < 4; ++r) {
                float v = fmaxf(acc[mf][nf][r] + bv, 0.f);
                hTile[(rowl + r) * 128 + col] = (half_t)v;
            }
        }
    }
    __syncthreads();

    // out[row] = hTile[row] @ W2 + b2 ; 4 threads per row, 32 cols each
    {
        int row = tid >> 2, q = tid & 3;
        const f16x8* hr = (const f16x8*)(hTile + row * 128 + q * 32);
        float px = 0.f, py = 0.f, pz = 0.f, pw = 0.f;
#pragma unroll
        for (int j = 0; j < 4; ++j) {
            f16x8 hv = hr[j];
#pragma unroll
            for (int e = 0; e < 8; ++e) {
                float hf = (float)hv[e];
                const float* wv = sW2 + (q * 32 + j * 8 + e) * 4;
                px += hf * wv[0]; py += hf * wv[1];
                pz += hf * wv[2]; pw += hf * wv[3];
            }
        }
        px += __shfl_xor(px, 1); py += __shfl_xor(py, 1);
        pz += __shfl_xor(pz, 1); pw += __shfl_xor(pw, 1);
        px += __shfl_xor(px, 2); py += __shfl_xor(py, 2);
        pz += __shfl_xor(pz, 2); pw += __shfl_xor(pw, 2);
        int gr = m0 + row;
        if (q == 0 && gr < M) {
            float4 o = {px + b2[0], py + b2[1], pz + b2[2], pw + b2[3]};
            *reinterpret_cast<float4*>(out + (size_t)gr * 4) = o;
        }
    }
}

extern "C" void kernel_launch(void* const* d_in, const int* in_sizes, int n_in,
                              void* d_out, int out_size, void* d_ws, size_t ws_size,
                              hipStream_t stream) {
    const float* x  = (const float*)d_in[0];
    const int*   ei = (const int*)d_in[1];
    const float* Wl = (const float*)d_in[2];
    const float* bl = (const float*)d_in[3];
    const float* Wr = (const float*)d_in[4];
    const float* W1 = (const float*)d_in[5];
    const float* b1 = (const float*)d_in[6];
    const float* W2 = (const float*)d_in[7];
    const float* b2 = (const float*)d_in[8];
    float* out = (float*)d_out;

    char* w = (char*)d_ws;
    size_t o = 0;
    auto alloc = [&](size_t bytes) -> void* {
        void* p = w + o;
        o += (bytes + 255) & ~(size_t)255;
        return p;
    };
    int* deg     = (int*)alloc((size_t)N_NODES * 4);
    int* cursor  = (int*)alloc((size_t)N_NODES * 4);
    int* offsets = (int*)alloc((size_t)N_NODES * 4);
    int* bsum    = (int*)alloc((size_t)NBLK * 4);
    int* bscan   = (int*)alloc((size_t)NBLK * 4);
    int* csr     = (int*)alloc((size_t)N_EDGES * 4);
    half_t* aggH = (half_t*)alloc((size_t)N_NODES * HID * 2);
    half_t* xa   = (half_t*)alloc((size_t)N_NODES * HID * 2);
    half_t* xb   = (half_t*)alloc((size_t)N_NODES * HID * 2);
    half_t* WlT[3]; half_t* WrT[3];
    for (int l = 0; l < 3; ++l) {
        WlT[l] = (half_t*)alloc((size_t)256 * 256 * 2);
        WrT[l] = (half_t*)alloc((size_t)256 * 256 * 2);
    }
    half_t* W1T = (half_t*)alloc((size_t)128 * 256 * 2);

    const int* srcA = ei;
    const int* dstA = ei + N_EDGES;

    for (int l = 0; l < 3; ++l) {
        k_transw<<<256, 256, 0, stream>>>(Wl + (size_t)l * 65536, WlT[l], 256);
        k_transw<<<256, 256, 0, stream>>>(Wr + (size_t)l * 65536, WrT[l], 256);
    }
    k_transw<<<128, 256, 0, stream>>>(W1, W1T, 128);
    k_tohalf<<<(N_NODES * HID / 8 + 255) / 256, 256, 0, stream>>>(x, xa, N_NODES * HID / 8);

    hipMemsetAsync(deg, 0, (size_t)N_NODES * 4, stream);
    k_count<<<(N_EDGES + 255) / 256, 256, 0, stream>>>(dstA, deg);
    k_blocksum<<<NBLK, 256, 0, stream>>>(deg, bsum);
    k_scan_bsum<<<1, 64, 0, stream>>>(bsum, bscan);
    k_scan_final<<<NBLK, 256, 0, stream>>>(deg, bscan, offsets, cursor);
    k_fill_xcd<<<FILL_CHUNKS * 8, 256, 0, stream>>>(srcA, dstA, cursor, csr);

    const int mtiles = (N_NODES + 127) / 128;  // 782
    half_t* cur = xa;
    half_t* nxt = xb;
    for (int l = 0; l < 3; ++l) {
        k_aggregate_h<<<N_NODES / 4, 256, 0, stream>>>(cur, offsets, deg, csr, aggH);
        k_gemm_f16<256, true, true><<<mtiles, 512, 0, stream>>>(
            aggH, WlT[l], cur, WrT[l], bl + (size_t)l * 256, nxt, N_NODES, 1);
        half_t* tmp = cur; cur = nxt; nxt = tmp;
    }
    // fused: out = relu(cur@W1 + b1) @ W2 + b2
    k_mlp_head<<<mtiles, 512, 0, stream>>>(cur, W1T, b1, W2, b2, out, N_NODES);
}

// Round 12
// 781.123 us; speedup vs baseline: 1.7612x; 1.0302x over previous
//
#include <hip/hip_runtime.h>

#define N_NODES 100000
#define N_EDGES 1600000
#define HID 256

typedef _Float16 half_t;
using f16x8 = __attribute__((ext_vector_type(8))) half_t;
using f16x4 = __attribute__((ext_vector_type(4))) half_t;
using f32x4 = __attribute__((ext_vector_type(4))) float;

constexpr int SCAN_CHUNK = 1024;
constexpr int NBLK = (N_NODES + SCAN_CHUNK - 1) / SCAN_CHUNK; // 98
constexpr int FILL_EPB = 4096;
constexpr int FILL_CHUNKS = (N_EDGES + FILL_EPB - 1) / FILL_EPB; // 391

#define GLOAD_LDS16(gp, lp)                                                    \
    __builtin_amdgcn_global_load_lds(                                         \
        (const __attribute__((address_space(1))) void*)(gp),                  \
        (__attribute__((address_space(3))) void*)(lp), 16, 0, 0)

template <int N>
__device__ __forceinline__ void vmwait() {
    asm volatile("s_waitcnt vmcnt(%0)" :: "n"(N) : "memory");
}

// ---------------- CSR build ----------------
__global__ void k_count(const int* __restrict__ dst, int* __restrict__ deg) {
    int e = blockIdx.x * 256 + threadIdx.x;
    if (e < N_EDGES) atomicAdd(&deg[dst[e]], 1);
}

__global__ void k_blocksum(const int* __restrict__ deg, int* __restrict__ bsum) {
    __shared__ int sm[4];
    int b = blockIdx.x, t = threadIdx.x;
    int base = b * SCAN_CHUNK;
    int s = 0;
    for (int i = 0; i < 4; ++i) {
        int idx = base + t + i * 256;
        if (idx < N_NODES) s += deg[idx];
    }
    for (int off = 32; off; off >>= 1) s += __shfl_down(s, off);
    if ((t & 63) == 0) sm[t >> 6] = s;
    __syncthreads();
    if (t == 0) bsum[b] = sm[0] + sm[1] + sm[2] + sm[3];
}

__global__ void k_scan_bsum(const int* __restrict__ bsum, int* __restrict__ bscan) {
    if (threadIdx.x == 0) {
        int r = 0;
        for (int i = 0; i < NBLK; ++i) { bscan[i] = r; r += bsum[i]; }
    }
}

__global__ void k_scan_final(const int* __restrict__ deg, const int* __restrict__ bscan,
                             int* __restrict__ offsets, int* __restrict__ cursor) {
    __shared__ int sm[256];
    int b = blockIdx.x, t = threadIdx.x;
    int base = b * SCAN_CHUNK + t * 4;
    int c[4];
    for (int e = 0; e < 4; ++e) {
        int idx = base + e;
        c[e] = (idx < N_NODES) ? deg[idx] : 0;
    }
    int s = c[0] + c[1] + c[2] + c[3];
    sm[t] = s;
    __syncthreads();
    for (int off = 1; off < 256; off <<= 1) {
        int v = (t >= off) ? sm[t - off] : 0;
        __syncthreads();
        sm[t] += v;
        __syncthreads();
    }
    int run = sm[t] - s + bscan[b];
    for (int e = 0; e < 4; ++e) {
        int idx = base + e;
        if (idx < N_NODES) { offsets[idx] = run; cursor[idx] = run; }
        run += c[e];
    }
}

// XCD-partitioned fill (R10 win): full-line writebacks per XCD-local slice.
__global__ __launch_bounds__(256) void k_fill_xcd(
    const int* __restrict__ src, const int* __restrict__ dst,
    int* __restrict__ cursor, int* __restrict__ csr) {
    const int part = blockIdx.x & 7;
    const int chunk = blockIdx.x >> 3;
    const int lo = part * (N_NODES / 8);
    const int hi = lo + (N_NODES / 8);
    const int ebeg = chunk * FILL_EPB + threadIdx.x;
    const int eend = min((chunk + 1) * FILL_EPB, N_EDGES);
    for (int e = ebeg; e < eend; e += 256) {
        int d = dst[e];
        if (d >= lo && d < hi) {
            int pos = atomicAdd(&cursor[d], 1);
            csr[pos] = src[e];
        }
    }
}

// ---------------- fp32 -> fp16 convert ----------------
__global__ void k_tohalf(const float* __restrict__ in, half_t* __restrict__ out, int n8) {
    int i = blockIdx.x * 256 + threadIdx.x;
    if (i < n8) {
        float4 a = *reinterpret_cast<const float4*>(in + (size_t)i * 8);
        float4 b = *reinterpret_cast<const float4*>(in + (size_t)i * 8 + 4);
        f16x8 h;
        h[0] = (half_t)a.x; h[1] = (half_t)a.y; h[2] = (half_t)a.z; h[3] = (half_t)a.w;
        h[4] = (half_t)b.x; h[5] = (half_t)b.y; h[6] = (half_t)b.z; h[7] = (half_t)b.w;
        *reinterpret_cast<f16x8*>(out + (size_t)i * 8) = h;
    }
}

// ---------------- mean aggregation -> fp16 (at line-rate floor) -----------
__global__ __launch_bounds__(256) void k_aggregate_h(
    const half_t* __restrict__ xh, const int* __restrict__ offsets,
    const int* __restrict__ deg, const int* __restrict__ csr,
    half_t* __restrict__ aggH) {
    int wave = threadIdx.x >> 6;
    int lane = threadIdx.x & 63;
    int node = blockIdx.x * 4 + wave;
    int off = offsets[node];
    int dg = deg[node];
    const size_t lo4 = (size_t)lane * 4;
    float4 a0 = {0.f, 0.f, 0.f, 0.f}, a1 = a0, a2 = a0, a3 = a0;
    int j = 0;
    for (; j + 4 <= dg; j += 4) {
        int s0 = csr[off + j + 0];
        int s1 = csr[off + j + 1];
        int s2 = csr[off + j + 2];
        int s3 = csr[off + j + 3];
        f16x4 v0 = *reinterpret_cast<const f16x4*>(xh + (size_t)s0 * HID + lo4);
        f16x4 v1 = *reinterpret_cast<const f16x4*>(xh + (size_t)s1 * HID + lo4);
        f16x4 v2 = *reinterpret_cast<const f16x4*>(xh + (size_t)s2 * HID + lo4);
        f16x4 v3 = *reinterpret_cast<const f16x4*>(xh + (size_t)s3 * HID + lo4);
        a0.x += (float)v0[0]; a0.y += (float)v0[1]; a0.z += (float)v0[2]; a0.w += (float)v0[3];
        a1.x += (float)v1[0]; a1.y += (float)v1[1]; a1.z += (float)v1[2]; a1.w += (float)v1[3];
        a2.x += (float)v2[0]; a2.y += (float)v2[1]; a2.z += (float)v2[2]; a2.w += (float)v2[3];
        a3.x += (float)v3[0]; a3.y += (float)v3[1]; a3.z += (float)v3[2]; a3.w += (float)v3[3];
    }
    for (; j < dg; ++j) {
        int s = csr[off + j];
        f16x4 v = *reinterpret_cast<const f16x4*>(xh + (size_t)s * HID + lo4);
        a0.x += (float)v[0]; a0.y += (float)v[1]; a0.z += (float)v[2]; a0.w += (float)v[3];
    }
    float av[4];
    av[0] = (a0.x + a1.x) + (a2.x + a3.x);
    av[1] = (a0.y + a1.y) + (a2.y + a3.y);
    av[2] = (a0.z + a1.z) + (a2.z + a3.z);
    av[3] = (a0.w + a1.w) + (a2.w + a3.w);
    float inv = 1.0f / (float)(dg > 0 ? dg : 1);
    f16x4 hi;
#pragma unroll
    for (int c = 0; c < 4; ++c) hi[c] = (half_t)(av[c] * inv);
    *reinterpret_cast<f16x4*>(aggH + (size_t)node * HID + lo4) = hi;
}

// ---------------- weight transpose to fp16: [col][k] ----------------------
__global__ void k_transw(const float* __restrict__ W, half_t* __restrict__ out, int ncols) {
    int col = blockIdx.x;
    int k = threadIdx.x;
    out[(size_t)col * 256 + k] = (half_t)W[(size_t)k * ncols + col];
}

// ---------------- layer GEMM: 256x256 tile, mixed-depth buffering ---------
// C[M][256] = relu(bias + A1@B1 + A2@B2), K=256/op, fp16 in / fp16 out.
// 8 waves as 4m x 2n (wave tile 64x128). B: 3-buf depth-2; A: 2-buf depth-1.
// Per step t: barrier1; issue B(t+2),A(t+1); vmwait<4> (A(t) landed, newer
// B(t+2)+A(t+1) stay in flight); barrier2; 32 MFMAs. LDS 80KB, 1 block/CU.
// Halves B re-staging vs BM=128 (staged bytes/layer 302->202 MB).
__global__ __launch_bounds__(512, 2) void k_gemm_l(
    const half_t* __restrict__ A1, const half_t* __restrict__ B1,
    const half_t* __restrict__ A2, const half_t* __restrict__ B2,
    const float* __restrict__ bias, half_t* __restrict__ C, int M) {
    constexpr int NSTEPS = 16;
    __shared__ f16x8 sA[2][1024];   // [kg(4)][row(256)]
    __shared__ f16x8 sB[3][1024];   // [kg(4)][col(256)]

    const int tid = threadIdx.x;
    const int lane = tid & 63;
    const int m0 = blockIdx.x * 256;
    const int l16 = lane & 15, fkg = lane >> 4;
    const int wid = tid >> 6, wm = wid >> 1, wn = wid & 1;  // 4m x 2n
    const int aBase = fkg * 256 + wm * 64 + l16;
    const int bBase = fkg * 256 + wn * 128 + l16;

    f32x4 acc[4][8] = {};

    auto STAGE_B = [&](int s, int buf) {
        const int kk = (s & 7) * 32;
        const half_t* Bp = (s >> 3) ? B2 : B1;
#pragma unroll
        for (int j = 0; j < 2; ++j) {
            int c = tid + j * 512;
            GLOAD_LDS16(Bp + (size_t)(c & 255) * 256 + kk + (c >> 8) * 8, &sB[buf][c]);
        }
    };
    auto STAGE_A = [&](int s, int buf) {
        const int kk = (s & 7) * 32;
        const half_t* Ap = (s >> 3) ? A2 : A1;
#pragma unroll
        for (int j = 0; j < 2; ++j) {
            int c = tid + j * 512;
            int gr = min(m0 + (c & 255), M - 1);
            GLOAD_LDS16(Ap + (size_t)gr * 256 + kk + (c >> 8) * 8, &sA[buf][c]);
        }
    };

    STAGE_B(0, 0);
    STAGE_B(1, 1);
    STAGE_A(0, 0);

#pragma unroll
    for (int t = 0; t < NSTEPS; ++t) {
        const int ab = t & 1;
        const int bb = t % 3;
        // barrier 1: compute(t-1) done everywhere -> bufs reusable
        __builtin_amdgcn_s_barrier();
        __builtin_amdgcn_sched_barrier(0);
        if (t + 2 < NSTEPS) STAGE_B(t + 2, (t + 2) % 3);
        if (t + 1 < NSTEPS) STAGE_A(t + 1, (t + 1) & 1);
        // wait for stage t: newer-than-A(t) = B(t+2)(2) + A(t+1)(2)
        if (t + 2 < NSTEPS) vmwait<4>();
        else if (t + 1 < NSTEPS) vmwait<2>();
        else vmwait<0>();
        // barrier 2: everyone's stage-t data landed
        __builtin_amdgcn_s_barrier();
        __builtin_amdgcn_sched_barrier(0);

        f16x8 ah[4];
#pragma unroll
        for (int mf = 0; mf < 4; ++mf) ah[mf] = sA[ab][aBase + mf * 16];
        __builtin_amdgcn_s_setprio(1);
#pragma unroll
        for (int nf = 0; nf < 8; ++nf) {
            f16x8 bh = sB[bb][bBase + nf * 16];
#pragma unroll
            for (int mf = 0; mf < 4; ++mf)
                acc[mf][nf] = __builtin_amdgcn_mfma_f32_16x16x32_f16(ah[mf], bh, acc[mf][nf], 0, 0, 0);
        }
        __builtin_amdgcn_s_setprio(0);
    }

    // epilogue: row = m0+wm*64+mf*16+(lane>>4)*4+r, col = wn*128+nf*16+l16
#pragma unroll
    for (int mf = 0; mf < 4; ++mf) {
        int row = m0 + wm * 64 + mf * 16 + (lane >> 4) * 4;
#pragma unroll
        for (int nf = 0; nf < 8; ++nf) {
            int col = wn * 128 + nf * 16 + l16;
            float bv = bias[col];
#pragma unroll
            for (int r = 0; r < 4; ++r) {
                int gr = row + r;
                if (gr < M)
                    C[(size_t)gr * 256 + col] = (half_t)fmaxf(acc[mf][nf][r] + bv, 0.f);
            }
        }
    }
}

// ---------------- fused MLP + head: out = relu(x@W1+b1) @ W2 + b2 ---------
__global__ __launch_bounds__(512, 4) void k_mlp_head(
    const half_t* __restrict__ A1, const half_t* __restrict__ B1,
    const float* __restrict__ b1, const float* __restrict__ W2,
    const float* __restrict__ b2, float* __restrict__ out, int M) {
    constexpr int NSTEPS = 8;
    __shared__ f16x8 sAB[3 * 512 + 3 * 512];  // 48KB staging; hTile aliases [0,32KB)
    __shared__ float sW2[512];                // W2 [128][4]
    f16x8 (*sA)[512] = (f16x8(*)[512])sAB;
    f16x8 (*sB)[512] = (f16x8(*)[512])(sAB + 3 * 512);
    half_t* hTile = (half_t*)sAB;

    const int tid = threadIdx.x;
    const int lane = tid & 63;
    const int m0 = blockIdx.x * 128;
    const int skg = tid >> 7;
    const int srow = tid & 127;
    const int grow = min(m0 + srow, M - 1);
    const int l16 = lane & 15, fkg = lane >> 4;
    const int wid = tid >> 6, wm = wid >> 2, wn = wid & 3;
    const int aBase = fkg * 128 + wm * 64 + l16;
    const int bBase = fkg * 128 + wn * 32 + l16;

    sW2[tid & 511] = W2[tid & 511];
    asm volatile("s_waitcnt lgkmcnt(0)" ::: "memory");

    f32x4 acc[4][2] = {};

    auto STAGE = [&](int s, int buf) {
        const int kk = s * 32;
        int col = tid & 127;
        int ckg = tid >> 7;
        GLOAD_LDS16(B1 + (size_t)col * 256 + kk + ckg * 8, &sB[buf][tid]);
        GLOAD_LDS16(A1 + (size_t)grow * 256 + kk + skg * 8, &sA[buf][tid]);
    };

    STAGE(0, 0);
    STAGE(1, 1);

#pragma unroll
    for (int t = 0; t < NSTEPS; ++t) {
        const int buf = t % 3;
        __builtin_amdgcn_s_barrier();
        __builtin_amdgcn_sched_barrier(0);
        if (t + 2 < NSTEPS) STAGE(t + 2, (t + 2) % 3);
        if (t + 2 < NSTEPS) vmwait<4>();
        else if (t + 1 < NSTEPS) vmwait<2>();
        else vmwait<0>();
        __builtin_amdgcn_s_barrier();
        __builtin_amdgcn_sched_barrier(0);

        f16x8 ah[4];
#pragma unroll
        for (int mf = 0; mf < 4; ++mf) ah[mf] = sA[buf][aBase + mf * 16];
        __builtin_amdgcn_s_setprio(1);
#pragma unroll
        for (int nf = 0; nf < 2; ++nf) {
            f16x8 bh = sB[buf][bBase + nf * 16];
#pragma unroll
            for (int mf = 0; mf < 4; ++mf)
                acc[mf][nf] = __builtin_amdgcn_mfma_f32_16x16x32_f16(ah[mf], bh, acc[mf][nf], 0, 0, 0);
        }
        __builtin_amdgcn_s_setprio(0);
    }

    __syncthreads();
#pragma unroll
    for (int mf = 0; mf < 4; ++mf) {
        int rowl = wm * 64 + mf * 16 + (lane >> 4) * 4;
#pragma unroll
        for (int nf = 0; nf < 2; ++nf) {
            int col = wn * 32 + nf * 16 + l16;
            float bv = b1[col];
#pragma unroll
            for (int r = 0; r < 4; ++r) {
                float v = fmaxf(acc[mf][nf][r] + bv, 0.f);
                hTile[(rowl + r) * 128 + col] = (half_t)v;
            }
        }
    }
    __syncthreads();

    {
        int row = tid >> 2, q = tid & 3;
        const f16x8* hr = (const f16x8*)(hTile + row * 128 + q * 32);
        float px = 0.f, py = 0.f, pz = 0.f, pw = 0.f;
#pragma unroll
        for (int j = 0; j < 4; ++j) {
            f16x8 hv = hr[j];
#pragma unroll
            for (int e = 0; e < 8; ++e) {
                float hf = (float)hv[e];
                const float* wv = sW2 + (q * 32 + j * 8 + e) * 4;
                px += hf * wv[0]; py += hf * wv[1];
                pz += hf * wv[2]; pw += hf * wv[3];
            }
        }
        px += __shfl_xor(px, 1); py += __shfl_xor(py, 1);
        pz += __shfl_xor(pz, 1); pw += __shfl_xor(pw, 1);
        px += __shfl_xor(px, 2); py += __shfl_xor(py, 2);
        pz += __shfl_xor(pz, 2); pw += __shfl_xor(pw, 2);
        int gr = m0 + row;
        if (q == 0 && gr < M) {
            float4 o = {px + b2[0], py + b2[1], pz + b2[2], pw + b2[3]};
            *reinterpret_cast<float4*>(out + (size_t)gr * 4) = o;
        }
    }
}

extern "C" void kernel_launch(void* const* d_in, const int* in_sizes, int n_in,
                              void* d_out, int out_size, void* d_ws, size_t ws_size,
                              hipStream_t stream) {
    const float* x  = (const float*)d_in[0];
    const int*   ei = (const int*)d_in[1];
    const float* Wl = (const float*)d_in[2];
    const float* bl = (const float*)d_in[3];
    const float* Wr = (const float*)d_in[4];
    const float* W1 = (const float*)d_in[5];
    const float* b1 = (const float*)d_in[6];
    const float* W2 = (const float*)d_in[7];
    const float* b2 = (const float*)d_in[8];
    float* out = (float*)d_out;

    char* w = (char*)d_ws;
    size_t o = 0;
    auto alloc = [&](size_t bytes) -> void* {
        void* p = w + o;
        o += (bytes + 255) & ~(size_t)255;
        return p;
    };
    int* deg     = (int*)alloc((size_t)N_NODES * 4);
    int* cursor  = (int*)alloc((size_t)N_NODES * 4);
    int* offsets = (int*)alloc((size_t)N_NODES * 4);
    int* bsum    = (int*)alloc((size_t)NBLK * 4);
    int* bscan   = (int*)alloc((size_t)NBLK * 4);
    int* csr     = (int*)alloc((size_t)N_EDGES * 4);
    half_t* aggH = (half_t*)alloc((size_t)N_NODES * HID * 2);
    half_t* xa   = (half_t*)alloc((size_t)N_NODES * HID * 2);
    half_t* xb   = (half_t*)alloc((size_t)N_NODES * HID * 2);
    half_t* WlT[3]; half_t* WrT[3];
    for (int l = 0; l < 3; ++l) {
        WlT[l] = (half_t*)alloc((size_t)256 * 256 * 2);
        WrT[l] = (half_t*)alloc((size_t)256 * 256 * 2);
    }
    half_t* W1T = (half_t*)alloc((size_t)128 * 256 * 2);

    const int* srcA = ei;
    const int* dstA = ei + N_EDGES;

    for (int l = 0; l < 3; ++l) {
        k_transw<<<256, 256, 0, stream>>>(Wl + (size_t)l * 65536, WlT[l], 256);
        k_transw<<<256, 256, 0, stream>>>(Wr + (size_t)l * 65536, WrT[l], 256);
    }
    k_transw<<<128, 256, 0, stream>>>(W1, W1T, 128);
    k_tohalf<<<(N_NODES * HID / 8 + 255) / 256, 256, 0, stream>>>(x, xa, N_NODES * HID / 8);

    hipMemsetAsync(deg, 0, (size_t)N_NODES * 4, stream);
    k_count<<<(N_EDGES + 255) / 256, 256, 0, stream>>>(dstA, deg);
    k_blocksum<<<NBLK, 256, 0, stream>>>(deg, bsum);
    k_scan_bsum<<<1, 64, 0, stream>>>(bsum, bscan);
    k_scan_final<<<NBLK, 256, 0, stream>>>(deg, bscan, offsets, cursor);
    k_fill_xcd<<<FILL_CHUNKS * 8, 256, 0, stream>>>(srcA, dstA, cursor, csr);

    const int mtiles128 = (N_NODES + 127) / 128;  // 782
    const int mtiles256 = (N_NODES + 255) / 256;  // 391
    half_t* cur = xa;
    half_t* nxt = xb;
    for (int l = 0; l < 3; ++l) {
        k_aggregate_h<<<N_NODES / 4, 256, 0, stream>>>(cur, offsets, deg, csr, aggH);
        // nxt(fp16) = relu(bl + agg@Wl + cur@Wr), 256x256 tiles
        k_gemm_l<<<mtiles256, 512, 0, stream>>>(
            aggH, WlT[l], cur, WrT[l], bl + (size_t)l * 256, nxt, N_NODES);
        half_t* tmp = cur; cur = nxt; nxt = tmp;
    }
    // fused: out = relu(cur@W1 + b1) @ W2 + b2
    k_mlp_head<<<mtiles128, 512, 0, stream>>>(cur, W1T, b1, W2, b2, out, N_NODES);
}